// Round 4
// baseline (6035.979 us; speedup 1.0000x reference)
//
#include <hip/hip_runtime.h>
#include <cstddef>
#include <cmath>

// ---------------- problem constants ----------------
constexpr int CB  = 16;
constexpr int CS  = 128;
constexpr int CD  = 384;
constexpr int CDF = 1536;
constexpr int CH  = 2;
constexpr int CL  = 6;
constexpr int CNM = 80;
constexpr int CLOUT = 1024;
constexpr int CDH = 192;

typedef __bf16 bf16x8 __attribute__((ext_vector_type(8)));
typedef float  f32x4  __attribute__((ext_vector_type(4)));

// =====================================================================
// ======  bf16 MFMA GEMM (verified padded-LDS staging)  ===============
// =====================================================================
constexpr int LDT = 72;
__global__ __launch_bounds__(256) void mm_bf16(
    const __bf16* __restrict__ A, long lda, long sA1, long sA2,
    const __bf16* __restrict__ Bt, long ldb, long sB1, long sB2,
    const float* __restrict__ bias, const float* __restrict__ resid,
    void* __restrict__ Cp, long ldc, long sC1, long sC2,
    int M, int N, int K, int zdiv, int relu, int outBf, float scale)
{
    int z = blockIdx.z;
    int zb = z / zdiv, zh = z % zdiv;
    const __bf16* Ab = A  + (long)zb * sA1 + (long)zh * sA2;
    const __bf16* Bb = Bt + (long)zb * sB1 + (long)zh * sB2;
    long coff = (long)zb * sC1 + (long)zh * sC2;

    __shared__ __attribute__((aligned(16))) __bf16 As[128 * LDT];
    __shared__ __attribute__((aligned(16))) __bf16 Bs[128 * LDT];

    int tid  = threadIdx.x;
    int lane = tid & 63;
    int wave = tid >> 6;
    int quad = lane >> 4;
    int l16  = lane & 15;
    int wm = (wave >> 1) * 64;
    int wn = (wave & 1) * 64;

    int mBase = blockIdx.y * 128;
    int nBase = blockIdx.x * 128;

    int trow  = tid >> 3;
    int tcol8 = (tid & 7) * 8;

    f32x4 acc[4][4] = {};

    for (int k0 = 0; k0 < K; k0 += 64) {
#pragma unroll
        for (int p = 0; p < 4; ++p) {
            int r = p * 32 + trow;
            const __bf16* ga = Ab + (long)(mBase + r) * lda + k0 + tcol8;
            *(uint4*)(&As[r * LDT + tcol8]) = *(const uint4*)ga;
            int gn = nBase + r; gn = gn < N ? gn : N - 1;
            const __bf16* gb = Bb + (long)gn * ldb + k0 + tcol8;
            *(uint4*)(&Bs[r * LDT + tcol8]) = *(const uint4*)gb;
        }
        __syncthreads();
#pragma unroll
        for (int ks = 0; ks < 2; ++ks) {
            int kof = ks * 32 + quad * 8;
            bf16x8 af[4], bfr[4];
#pragma unroll
            for (int mt = 0; mt < 4; ++mt)
                af[mt] = *(const bf16x8*)(&As[(wm + mt * 16 + l16) * LDT + kof]);
#pragma unroll
            for (int nt = 0; nt < 4; ++nt)
                bfr[nt] = *(const bf16x8*)(&Bs[(wn + nt * 16 + l16) * LDT + kof]);
#pragma unroll
            for (int mt = 0; mt < 4; ++mt)
#pragma unroll
                for (int nt = 0; nt < 4; ++nt)
                    acc[mt][nt] = __builtin_amdgcn_mfma_f32_16x16x32_bf16(
                        af[mt], bfr[nt], acc[mt][nt], 0, 0, 0);
        }
        __syncthreads();
    }

#pragma unroll
    for (int mt = 0; mt < 4; ++mt) {
#pragma unroll
        for (int nt = 0; nt < 4; ++nt) {
            int col = nBase + wn + nt * 16 + l16;
            if (col >= N) continue;
            int row0 = mBase + wm + mt * 16 + quad * 4;
            float bv = bias ? bias[col] : 0.f;
#pragma unroll
            for (int r = 0; r < 4; ++r) {
                long off = coff + (long)(row0 + r) * ldc + col;
                float v = acc[mt][nt][r] * scale + bv;
                if (resid) v += resid[off];
                if (relu) v = fmaxf(v, 0.f);
                if (outBf) ((__bf16*)Cp)[off] = (__bf16)v;
                else       ((float*)Cp)[off] = v;
            }
        }
    }
}

// =====================================================================
// ======  Windowed K=3 conv as MFMA GEMM — 8-wave + reg-dbuf  =========
// =====================================================================
// Apad: [NB][Tp2][Cc] bf16, zero pad rows at 0 and Tp2-1 (data t at row 1+t).
// W: [O][3*Cc] bf16, (kk,c) order.
// 512 thr = 8 waves (2m x 4n), wave tile 64 x WN, block 128 x 4*WN.
// K staged in 32-col chunks (LDT2=40).
// R4 post-mortem of R3 (4-wave fat tiles, MfmaUtil 18%, Occ 10.8%):
// latency-bound — staging global->LDS fully exposed between barriers.
// Fix: 8 waves restore TLP; REGISTER double-buffer hides global latency:
//   barrier -> regs->LDS -> barrier -> issue next-chunk loads -> compute.
template<int WN>
__global__ __launch_bounds__(512) void conv_mfma3(
    const __bf16* __restrict__ Apad, const __bf16* __restrict__ W,
    const float* __restrict__ bias, const float* __restrict__ resid,
    void* __restrict__ Cp, long ldc, long sC1,
    int T, int Tp2, int Cc, int O, int relu, int outBf)
{
    constexpr int BN    = 4 * WN;              // 256 or 128
    constexpr int NT    = WN / 16;             // 4 or 2
    constexpr int LDT2  = 40;                  // 32 data cols + 8 pad
    constexpr int BITER = 3 * BN * 4 / 512;    // B uint4 per thread: 6 or 3

    int z = blockIdx.z;
    int t0 = blockIdx.y * 128;
    int nBase = blockIdx.x * BN;
    const __bf16* Ab = Apad + ((long)z * Tp2 + t0) * Cc;   // LDS row r <-> pad row t0+r

    __shared__ __attribute__((aligned(16))) __bf16 As[130 * LDT2];
    __shared__ __attribute__((aligned(16))) __bf16 Bs[3][BN * LDT2];

    int tid  = threadIdx.x;
    int lane = tid & 63;
    int wave = tid >> 6;         // 0..7
    int quad = lane >> 4;
    int l16  = lane & 15;
    int wm = (wave >> 2) * 64;   // 0,64
    int wn = (wave & 3) * WN;    // 0..3*WN

    f32x4 acc[4][NT] = {};

    long ldw = 3L * Cc;

    uint4 aR[2];
    uint4 bR[BITER];

    // ---- global -> regs (issue; no LDS traffic) ----
    auto loadA = [&](int c0) {
#pragma unroll
        for (int i = 0; i < 2; ++i) {
            int u = tid + i * 512;
            if (u < 520) {
                int r = u >> 2, cc = (u & 3) * 8;
                aR[i] = *(const uint4*)(Ab + (long)r * Cc + c0 + cc);
            }
        }
    };
    auto loadB = [&](int c0) {
#pragma unroll
        for (int i = 0; i < BITER; ++i) {
            int u = tid + i * 512;
            int kk = u / (BN * 4), rr = (u >> 2) & (BN - 1), cc = (u & 3) * 8;
            bR[i] = *(const uint4*)(W + (long)(nBase + rr) * ldw + kk * Cc + c0 + cc);
        }
    };
    // ---- regs -> LDS ----
    auto storeA = [&]() {
#pragma unroll
        for (int i = 0; i < 2; ++i) {
            int u = tid + i * 512;
            if (u < 520) {
                int r = u >> 2, cc = (u & 3) * 8;
                *(uint4*)(&As[r * LDT2 + cc]) = aR[i];
            }
        }
    };
    auto storeB = [&]() {
#pragma unroll
        for (int i = 0; i < BITER; ++i) {
            int u = tid + i * 512;
            int kk = u / (BN * 4), rr = (u >> 2) & (BN - 1), cc = (u & 3) * 8;
            *(uint4*)(&Bs[kk][rr * LDT2 + cc]) = bR[i];
        }
    };

    loadA(0);
    loadB(0);

    for (int c0 = 0; c0 < Cc; c0 += 32) {
        __syncthreads();              // previous chunk's readers done
        storeA();
        storeB();
        __syncthreads();              // LDS ready
        if (c0 + 32 < Cc) {           // prefetch next chunk; latency hides
            loadA(c0 + 32);           // under the MFMA/ds_read phase below
            loadB(c0 + 32);
        }
#pragma unroll
        for (int kk = 0; kk < 3; ++kk) {
            bf16x8 a[4], b[NT];
#pragma unroll
            for (int mt = 0; mt < 4; ++mt)
                a[mt] = *(const bf16x8*)(&As[(wm + mt * 16 + l16 + kk) * LDT2 + quad * 8]);
#pragma unroll
            for (int nt = 0; nt < NT; ++nt)
                b[nt] = *(const bf16x8*)(&Bs[kk][(wn + nt * 16 + l16) * LDT2 + quad * 8]);
#pragma unroll
            for (int mt = 0; mt < 4; ++mt)
#pragma unroll
                for (int nt = 0; nt < NT; ++nt)
                    acc[mt][nt] = __builtin_amdgcn_mfma_f32_16x16x32_bf16(
                        a[mt], b[nt], acc[mt][nt], 0, 0, 0);
        }
    }

    // epilogue: C/D layout col=l16, row=quad*4+r
#pragma unroll
    for (int mt = 0; mt < 4; ++mt) {
#pragma unroll
        for (int nt = 0; nt < NT; ++nt) {
            int col = nBase + wn + nt * 16 + l16;
            int trow = t0 + wm + mt * 16 + quad * 4;
            float bv = bias[col];
#pragma unroll
            for (int r = 0; r < 4; ++r) {
                long off = (long)z * sC1 + (long)(trow + r) * ldc + col;
                float v = acc[mt][nt][r] + bv;
                if (resid) v += resid[off];
                if (relu) v = fmaxf(v, 0.f);
                if (outBf) ((__bf16*)Cp)[off] = (__bf16)v;
                else       ((float*)Cp)[off] = v;
            }
        }
    }
}

// =====================================================================
// ======  Fused flash attention (QK^T -> softmax -> PV), DH=192  ======
// =====================================================================
__global__ __launch_bounds__(512) void flash_attn(
    const __bf16* __restrict__ qkv, __bf16* __restrict__ o, int T, float scl)
{
    int z = blockIdx.y;
    int b = z >> 1, h = z & 1;
    const __bf16* base = qkv + (long)b * T * 3 * CD + h * CDH;
    int qBase = blockIdx.x * 128;

    __shared__ __attribute__((aligned(16))) __bf16 Qs[128][200];
    __shared__ __attribute__((aligned(16))) __bf16 Ks[64][200];
    __shared__ __attribute__((aligned(16))) __bf16 Vt[192][72];
    __shared__ __attribute__((aligned(16))) __bf16 Ps[128][72];

    int tid  = threadIdx.x;
    int lane = tid & 63;
    int wave = tid >> 6;
    int quad = lane >> 4;
    int l16  = lane & 15;
    int wq   = wave * 16;

#pragma unroll
    for (int i = 0; i < 6; ++i) {
        int u = tid + i * 512;
        int r = u / 24, c = (u % 24) * 8;
        *(uint4*)(&Qs[r][c]) = *(const uint4*)(base + (long)(qBase + r) * 3 * CD + c);
    }

    f32x4 oacc[12];
#pragma unroll
    for (int j = 0; j < 12; ++j) oacc[j] = (f32x4){0.f, 0.f, 0.f, 0.f};
    float mrow[4], lrow[4];
#pragma unroll
    for (int r = 0; r < 4; ++r) { mrow[r] = -3.0e38f; lrow[r] = 0.f; }

    for (int kv0 = 0; kv0 < T; kv0 += 64) {
        __syncthreads();
#pragma unroll
        for (int i = 0; i < 3; ++i) {
            int u = tid + i * 512;
            int r = u / 24, c = (u % 24) * 8;
            *(uint4*)(&Ks[r][c]) = *(const uint4*)(base + CD + (long)(kv0 + r) * 3 * CD + c);
        }
        // V transpose staging: r = u&63 (kv row), c = (u>>6)*8 (d-block) ->
        // per write-instruction the 64 lanes write 64 consecutive Vt columns
        // (128 contiguous B = all 32 banks, <=2-way).  (R1 fix: was ~24-way.)
#pragma unroll
        for (int i = 0; i < 3; ++i) {
            int u = tid + i * 512;
            int r = u & 63, c = (u >> 6) * 8;
            uint4 pkt = *(const uint4*)(base + 2 * CD + (long)(kv0 + r) * 3 * CD + c);
            const __bf16* v8 = (const __bf16*)&pkt;
#pragma unroll
            for (int j = 0; j < 8; ++j) Vt[c + j][r] = v8[j];
        }
        __syncthreads();

        f32x4 s[4];
#pragma unroll
        for (int nt = 0; nt < 4; ++nt) s[nt] = (f32x4){0.f, 0.f, 0.f, 0.f};
#pragma unroll
        for (int ks = 0; ks < 6; ++ks) {
            bf16x8 aq = *(const bf16x8*)(&Qs[wq + l16][ks * 32 + quad * 8]);
#pragma unroll
            for (int nt = 0; nt < 4; ++nt) {
                bf16x8 bk = *(const bf16x8*)(&Ks[nt * 16 + l16][ks * 32 + quad * 8]);
                s[nt] = __builtin_amdgcn_mfma_f32_16x16x32_bf16(aq, bk, s[nt], 0, 0, 0);
            }
        }
        float alpha[4];
#pragma unroll
        for (int r = 0; r < 4; ++r) {
            float mx = -3.0e38f;
#pragma unroll
            for (int nt = 0; nt < 4; ++nt) {
                s[nt][r] *= scl;
                mx = fmaxf(mx, s[nt][r]);
            }
            mx = fmaxf(mx, __shfl_xor(mx, 1));
            mx = fmaxf(mx, __shfl_xor(mx, 2));
            mx = fmaxf(mx, __shfl_xor(mx, 4));
            mx = fmaxf(mx, __shfl_xor(mx, 8));
            float mnew = fmaxf(mrow[r], mx);
            alpha[r] = __expf(mrow[r] - mnew);
            mrow[r] = mnew;
            float rs = 0.f;
#pragma unroll
            for (int nt = 0; nt < 4; ++nt) {
                float e = __expf(s[nt][r] - mnew);
                s[nt][r] = e;
                rs += e;
            }
            rs += __shfl_xor(rs, 1);
            rs += __shfl_xor(rs, 2);
            rs += __shfl_xor(rs, 4);
            rs += __shfl_xor(rs, 8);
            lrow[r] = lrow[r] * alpha[r] + rs;
        }
#pragma unroll
        for (int r = 0; r < 4; ++r)
#pragma unroll
            for (int nt = 0; nt < 4; ++nt)
                Ps[wq + quad * 4 + r][nt * 16 + l16] = (__bf16)s[nt][r];
#pragma unroll
        for (int j = 0; j < 12; ++j)
#pragma unroll
            for (int r = 0; r < 4; ++r) oacc[j][r] *= alpha[r];
#pragma unroll
        for (int ks2 = 0; ks2 < 2; ++ks2) {
            bf16x8 ap = *(const bf16x8*)(&Ps[wq + l16][ks2 * 32 + quad * 8]);
#pragma unroll
            for (int nt = 0; nt < 12; ++nt) {
                bf16x8 bv = *(const bf16x8*)(&Vt[nt * 16 + l16][ks2 * 32 + quad * 8]);
                oacc[nt] = __builtin_amdgcn_mfma_f32_16x16x32_bf16(ap, bv, oacc[nt], 0, 0, 0);
            }
        }
    }

    __bf16* ob = o + ((long)b * T + qBase + wq + quad * 4) * CD + h * CDH + l16;
#pragma unroll
    for (int r = 0; r < 4; ++r) {
        float inv = 1.0f / lrow[r];
#pragma unroll
        for (int nt = 0; nt < 12; ++nt)
            ob[(long)r * CD + nt * 16] = (__bf16)(oacc[nt][r] * inv);
    }
}

// ---- LN: out32 = LN(a)*g+be ; bf16 padded copy ----
__global__ __launch_bounds__(CD) void ln_res(const float* __restrict__ a,
    const float* __restrict__ g, const float* __restrict__ be,
    float* __restrict__ out32, __bf16* __restrict__ outbf, int Tlog2)
{
    long r = blockIdx.x;
    int d = threadIdx.x;
    float v = a[r * CD + d];
    float s1 = v, s2 = v * v;
#pragma unroll
    for (int off = 32; off > 0; off >>= 1) {
        s1 += __shfl_down(s1, off);
        s2 += __shfl_down(s2, off);
    }
    __shared__ float sh1[CD / 64], sh2[CD / 64];
    int wv = d >> 6, ln = d & 63;
    if (ln == 0) { sh1[wv] = s1; sh2[wv] = s2; }
    __syncthreads();
    if (d == 0) {
        float t1 = 0.f, t2 = 0.f;
        for (int i = 0; i < CD / 64; ++i) { t1 += sh1[i]; t2 += sh2[i]; }
        sh1[0] = t1; sh2[0] = t2;
    }
    __syncthreads();
    float mean = sh1[0] * (1.0f / CD);
    float var  = sh2[0] * (1.0f / CD) - mean * mean;
    float res = (v - mean) * rsqrtf(var + 1e-5f) * g[d] + be[d];
    out32[r * CD + d] = res;
    int T = 1 << Tlog2;
    long bb = r >> Tlog2; int t = (int)(r & (T - 1));
    outbf[(bb * (T + 2) + t + 1) * CD + d] = (__bf16)res;
}

__global__ __launch_bounds__(CD) void f32_to_padbf16(const float* __restrict__ in,
    __bf16* __restrict__ out, int Tlog2)
{
    long r = blockIdx.x;
    int d = threadIdx.x;
    int T = 1 << Tlog2;
    long b = r >> Tlog2; int t = (int)(r & (T - 1));
    out[(b * (T + 2) + t + 1) * CD + d] = (__bf16)in[r * CD + d];
}

__global__ void zero_pads(__bf16* __restrict__ p, int Tp2, int C)
{
    int b = blockIdx.x >> 1;
    int which = blockIdx.x & 1;
    long row = (long)b * Tp2 + (which ? Tp2 - 1 : 0);
    for (int c = threadIdx.x; c < C; c += blockDim.x) p[row * C + c] = (__bf16)0.f;
}

__global__ __launch_bounds__(256) void tr_f32_bf16(const float* __restrict__ in,
    __bf16* __restrict__ out, int R, int C)
{
    __shared__ float t[32][33];
    int c0 = blockIdx.x * 32, r0 = blockIdx.y * 32;
    int tx = threadIdx.x & 31, ty = threadIdx.x >> 5;
#pragma unroll
    for (int i = 0; i < 4; ++i) {
        int rr = ty * 4 + i;
        int r = r0 + rr, c = c0 + tx;
        if (r < R && c < C) t[rr][tx] = in[(long)r * C + c];
    }
    __syncthreads();
#pragma unroll
    for (int i = 0; i < 4; ++i) {
        int cc = ty * 4 + i;
        int c = c0 + cc, r = r0 + tx;
        if (c < C && r < R) out[(long)c * R + r] = (__bf16)t[tx][cc];
    }
}

__global__ void convw_bf16(const float* __restrict__ w, __bf16* __restrict__ wt,
                           int O, int Cc)
{
    long total = (long)O * 3 * Cc;
    int KC = 3 * Cc;
    for (long i = (long)blockIdx.x * blockDim.x + threadIdx.x; i < total;
         i += (long)gridDim.x * blockDim.x) {
        int j = (int)(i % KC); long o = i / KC;
        int kk = j / Cc, c = j % Cc;
        wt[i] = (__bf16)w[(o * Cc + c) * 3 + kk];
    }
}

__global__ __launch_bounds__(CD) void embed_pe_kernel(const int* __restrict__ x,
    const float* __restrict__ emb, float* __restrict__ h)
{
    int bs = blockIdx.x;
    int d  = threadIdx.x;
    int s  = bs & (CS - 1);
    int tok = x[bs];
    int i = d >> 1;
    float ang = (float)s * powf(10000.0f, -2.0f * (float)i / (float)CD);
    float pe = (d & 1) ? cosf(ang) : sinf(ang);
    h[(size_t)bs * CD + d] = emb[(size_t)tok * CD + d] + pe;
}

__global__ __launch_bounds__(CS) void lenreg_kernel(const int* __restrict__ y,
    int* __restrict__ idx, int* __restrict__ totals)
{
    __shared__ int ends[CS];
    int b = blockIdx.x, tid = threadIdx.x;
    if (tid == 0) {
        int acc = 0;
        for (int s = 0; s < CS; ++s) { acc += y[b * CS + s]; ends[s] = acc; }
    }
    __syncthreads();
    for (int t = tid; t < CLOUT; t += CS) idx[b * CLOUT + t] = CS - 1;
    if (tid == 0) totals[b] = ends[CS - 1];
    __syncthreads();
    int st = (tid == 0) ? 0 : ends[tid - 1];
    int en = ends[tid];
    for (int t = st; t < en; ++t) idx[b * CLOUT + t] = tid;
}

__global__ __launch_bounds__(CD) void gather_dual(const float* __restrict__ hph,
    const int* __restrict__ idx, const int* __restrict__ tot,
    float* __restrict__ h32, __bf16* __restrict__ hbf, int chunkBase)
{
    int rl = blockIdx.x;
    int rg = chunkBase + rl;
    int b = rg >> 10, t = rg & (CLOUT - 1);
    int d = threadIdx.x;
    int src = idx[rg];
    float v = (t < tot[b]) ? hph[((long)b * CS + src) * CD + d] : 0.f;
    h32[(long)rl * CD + d] = v;
    long bl = rl >> 10; int tl = rl & (CLOUT - 1);
    hbf[(bl * (CLOUT + 2) + tl + 1) * CD + d] = (__bf16)v;
}

// =====================================================================
// ===============  bf16 path driver  ==================================
// =====================================================================

static inline void mm(hipStream_t st, const __bf16* A, long lda, long sA1, long sA2,
    const __bf16* Bt, long ldb, long sB1, long sB2, const float* bias,
    const float* resid, void* C, long ldc, long sC1, long sC2, int M, int N, int K,
    int nz, int zdiv, int relu, int outBf, float scale)
{
    dim3 g((N + 127) / 128, M / 128, nz), b(256, 1, 1);
    hipLaunchKernelGGL(mm_bf16, g, b, 0, st, A, lda, sA1, sA2, Bt, ldb, sB1, sB2,
                       bias, resid, C, ldc, sC1, sC2, M, N, K, zdiv, relu, outBf, scale);
}

struct Scr {
    float *h32, *x32, *tmp32;
    __bf16 *hbf, *xbf, *qkv, *c1p, *o;
};

static size_t scr_layout(char* base, int NB, int T, Scr* s)
{
    auto align = [](size_t v) { return (v + 255) & ~(size_t)255; };
    size_t off = 0;
    long Tp2 = T + 2;
    if (s) s->h32 = (float*)(base + off);
    off = align(off + (size_t)NB * T * CD * 4);
    if (s) s->x32 = (float*)(base + off);
    off = align(off + (size_t)NB * T * CD * 4);
    if (s) s->tmp32 = (float*)(base + off);
    off = align(off + (size_t)NB * T * CD * 4);
    if (s) s->hbf = (__bf16*)(base + off);
    off = align(off + (size_t)NB * Tp2 * CD * 2);
    if (s) s->xbf = (__bf16*)(base + off);
    off = align(off + (size_t)NB * Tp2 * CD * 2);
    if (s) s->qkv = (__bf16*)(base + off);
    off = align(off + (size_t)NB * T * 3 * CD * 2);
    if (s) s->c1p = (__bf16*)(base + off);
    off = align(off + (size_t)NB * Tp2 * CDF * 2);
    if (s) s->o = (__bf16*)(base + off);
    off = align(off + (size_t)NB * T * CD * 2);
    return off;
}

// per-layer bf16 weight offsets (elements)
constexpr long W_QKV = 0;
constexpr long W_OUT = 442368;
constexpr long W_C1  = 589824;
constexpr long W_C2  = 2359296;
constexpr long WLAYER = 4128768;
constexpr long WSTACK = 6 * WLAYER;
constexpr long WTOT   = WSTACK + 30720;

static void convert_stack_weights(hipStream_t st, __bf16* wbuf,
    const float* qkv_w, const float* out_w, const float* c1w, const float* c2w)
{
    for (int l = 0; l < CL; ++l) {
        __bf16* wl = wbuf + (long)l * WLAYER;
        hipLaunchKernelGGL(tr_f32_bf16, dim3(36, 12), dim3(256), 0, st,
                           qkv_w + (long)l * CD * 3 * CD, wl + W_QKV, CD, 3 * CD);
        hipLaunchKernelGGL(tr_f32_bf16, dim3(12, 12), dim3(256), 0, st,
                           out_w + (long)l * CD * CD, wl + W_OUT, CD, CD);
        hipLaunchKernelGGL(convw_bf16, dim3(2048), dim3(256), 0, st,
                           c1w + (long)l * CDF * CD * 3, wl + W_C1, CDF, CD);
        hipLaunchKernelGGL(convw_bf16, dim3(2048), dim3(256), 0, st,
                           c2w + (long)l * CD * CDF * 3, wl + W_C2, CD, CDF);
    }
}

static void fft_block_bf16(hipStream_t st, const Scr& S, int NBc, int T, int tlog2,
    float* h32, const __bf16* wl,
    const float* qkv_b, const float* out_b,
    const float* g1, const float* b1, const float* c1b, const float* c2b,
    const float* g2, const float* b2)
{
    const int M = NBc * T;
    const long Tp2 = T + 2;
    const float scl = 1.0f / sqrtf((float)CDH);

    // qkv = h @ Wqkv + b
    mm(st, S.hbf + CD, CD, Tp2 * CD, 0, wl + W_QKV, CD, 0, 0, qkv_b, nullptr,
       S.qkv, 3 * CD, (long)T * 3 * CD, 0, T, 3 * CD, CD, NBc, 1, 0, 1, 1.f);

    // fused attention
    hipLaunchKernelGGL(flash_attn, dim3(T / 128, NBc * CH), dim3(512), 0, st,
                       S.qkv, S.o, T, scl);

    // tmp = o @ Wout + b + h (residual fused)
    mm(st, S.o, CD, 0, 0, wl + W_OUT, CD, 0, 0, out_b, h32,
       S.tmp32, CD, 0, 0, M, CD, CD, 1, 1, 0, 0, 1.f);

    // x = LN(tmp)
    hipLaunchKernelGGL(ln_res, dim3(M), dim3(CD), 0, st,
                       S.tmp32, g1, b1, S.x32, S.xbf, tlog2);

    // conv1: relu(conv(x)) -> c1p rows 1..T (bf16); 8-wave reg-dbuf, block 128x256
    hipLaunchKernelGGL((conv_mfma3<64>), dim3(CDF / 256, T / 128, NBc), dim3(512), 0, st,
                       S.xbf, wl + W_C1, c1b, nullptr,
                       (void*)(S.c1p + CDF), (long)CDF, Tp2 * CDF,
                       T, (int)Tp2, CD, CDF, 1, 1);

    // conv2 + resid -> tmp32 (fp32); block 128x128
    hipLaunchKernelGGL((conv_mfma3<32>), dim3(CD / 128, T / 128, NBc), dim3(512), 0, st,
                       S.c1p, wl + W_C2, c2b, S.x32,
                       S.tmp32, (long)CD, (long)T * CD,
                       T, (int)Tp2, CDF, CD, 0, 0);

    // h = LN(tmp)
    hipLaunchKernelGGL(ln_res, dim3(M), dim3(CD), 0, st,
                       S.tmp32, g2, b2, h32, S.hbf, tlog2);
}

extern "C" void kernel_launch(void* const* d_in, const int* in_sizes, int n_in,
                              void* d_out, int out_size, void* d_ws, size_t ws_size,
                              hipStream_t stream)
{
    (void)in_sizes; (void)out_size;

    const int* x = (const int*)d_in[0];
    const int* y = (const int*)d_in[1];
    const float* P[40];
    for (int i = 0; i < n_in && i < 40; ++i) P[i] = (const float*)d_in[i];

    size_t wbufB  = ((size_t)WTOT * 2 + 255) & ~(size_t)255;
    size_t hphB   = ((size_t)CB * CS * CD * 4 + 255) & ~(size_t)255;
    size_t idxB   = (((size_t)CB * CLOUT + CB) * 4 + 255) & ~(size_t)255;
    size_t fixedB = wbufB + hphB + idxB;

    size_t scrB = (ws_size > fixedB) ? (ws_size - fixedB) : 0;

    int NBmel = 1;
    for (int cand = 16; cand >= 1; cand >>= 1)
        if (scr_layout(nullptr, cand, CLOUT, nullptr) <= scrB) { NBmel = cand; break; }

    int NBph = 1;
    for (int cand = 16; cand >= 1; cand >>= 1)
        if (scr_layout(nullptr, cand, CS, nullptr) <= scrB) { NBph = cand; break; }

    char* base = (char*)d_ws;
    __bf16* wbuf = (__bf16*)base;
    float*  hPh  = (float*)(base + wbufB);
    int*    idxb = (int*)(base + wbufB + hphB);
    int*    totb = idxb + (long)CB * CLOUT;
    char*   scrbase = base + fixedB;

    // ================= phoneme encoder =================
    convert_stack_weights(stream, wbuf, P[3], P[5], P[9], P[11]);

    Scr Sp; scr_layout(scrbase, NBph, CS, &Sp);
    hipLaunchKernelGGL(zero_pads, dim3(NBph * 2), dim3(256), 0, stream, Sp.hbf, CS + 2, CD);
    hipLaunchKernelGGL(zero_pads, dim3(NBph * 2), dim3(256), 0, stream, Sp.xbf, CS + 2, CD);
    hipLaunchKernelGGL(zero_pads, dim3(NBph * 2), dim3(256), 0, stream, Sp.c1p, CS + 2, CDF);

    hipLaunchKernelGGL(embed_pe_kernel, dim3(CB * CS), dim3(CD), 0, stream, x, P[2], hPh);

    for (int c = 0; c < CB / NBph; ++c) {
        float* hch = hPh + (long)c * NBph * CS * CD;
        hipLaunchKernelGGL(f32_to_padbf16, dim3(NBph * CS), dim3(CD), 0, stream,
                           hch, Sp.hbf, 7);
        for (int l = 0; l < CL; ++l)
            fft_block_bf16(stream, Sp, NBph, CS, 7, hch, wbuf + (long)l * WLAYER,
                           P[4] + (long)l * 3 * CD, P[6] + (long)l * CD,
                           P[7] + (long)l * CD, P[8] + (long)l * CD,
                           P[10] + (long)l * CDF, P[12] + (long)l * CD,
                           P[13] + (long)l * CD, P[14] + (long)l * CD);
    }

    // ================= length regulation =================
    hipLaunchKernelGGL(lenreg_kernel, dim3(CB), dim3(CS), 0, stream, y, idxb, totb);

    // ================= mel decoder =================
    convert_stack_weights(stream, wbuf, P[15], P[17], P[21], P[23]);
    hipLaunchKernelGGL(tr_f32_bf16, dim3(3, 12), dim3(256), 0, stream,
                       P[37], wbuf + WSTACK, CD, CNM);

    Scr Sm; scr_layout(scrbase, NBmel, CLOUT, &Sm);
    hipLaunchKernelGGL(zero_pads, dim3(NBmel * 2), dim3(256), 0, stream, Sm.hbf, CLOUT + 2, CD);
    hipLaunchKernelGGL(zero_pads, dim3(NBmel * 2), dim3(256), 0, stream, Sm.xbf, CLOUT + 2, CD);
    hipLaunchKernelGGL(zero_pads, dim3(NBmel * 2), dim3(256), 0, stream, Sm.c1p, CLOUT + 2, CDF);

    for (int c = 0; c < CB / NBmel; ++c) {
        hipLaunchKernelGGL(gather_dual, dim3(NBmel * CLOUT), dim3(CD), 0, stream,
                           hPh, idxb, totb, Sm.h32, Sm.hbf, c * NBmel * CLOUT);
        for (int l = 0; l < CL; ++l)
            fft_block_bf16(stream, Sm, NBmel, CLOUT, 10, Sm.h32, wbuf + (long)l * WLAYER,
                           P[16] + (long)l * 3 * CD, P[18] + (long)l * CD,
                           P[19] + (long)l * CD, P[20] + (long)l * CD,
                           P[22] + (long)l * CDF, P[24] + (long)l * CD,
                           P[25] + (long)l * CD, P[26] + (long)l * CD);
        // final projection for this chunk
        mm(stream, Sm.hbf + CD, CD, (long)(CLOUT + 2) * CD, 0,
           wbuf + WSTACK, CD, 0, 0, P[38], nullptr,
           (float*)d_out + (long)c * NBmel * CLOUT * CNM, CNM, (long)CLOUT * CNM, 0,
           CLOUT, CNM, CD, NBmel, 1, 0, 0, 1.f);
    }
}

// Round 5
// 3506.798 us; speedup vs baseline: 1.7212x; 1.7212x over previous
//
#include <hip/hip_runtime.h>
#include <cstddef>
#include <cmath>

// ---------------- problem constants ----------------
constexpr int CB  = 16;
constexpr int CS  = 128;
constexpr int CD  = 384;
constexpr int CDF = 1536;
constexpr int CH  = 2;
constexpr int CL  = 6;
constexpr int CNM = 80;
constexpr int CLOUT = 1024;
constexpr int CDH = 192;

typedef __bf16 bf16x8 __attribute__((ext_vector_type(8)));
typedef float  f32x4  __attribute__((ext_vector_type(4)));

// =====================================================================
// ======  bf16 MFMA GEMM (verified padded-LDS staging)  ===============
// =====================================================================
constexpr int LDT = 72;
__global__ __launch_bounds__(256) void mm_bf16(
    const __bf16* __restrict__ A, long lda, long sA1, long sA2,
    const __bf16* __restrict__ Bt, long ldb, long sB1, long sB2,
    const float* __restrict__ bias, const float* __restrict__ resid,
    void* __restrict__ Cp, long ldc, long sC1, long sC2,
    int M, int N, int K, int zdiv, int relu, int outBf, float scale)
{
    int z = blockIdx.z;
    int zb = z / zdiv, zh = z % zdiv;
    const __bf16* Ab = A  + (long)zb * sA1 + (long)zh * sA2;
    const __bf16* Bb = Bt + (long)zb * sB1 + (long)zh * sB2;
    long coff = (long)zb * sC1 + (long)zh * sC2;

    __shared__ __attribute__((aligned(16))) __bf16 As[128 * LDT];
    __shared__ __attribute__((aligned(16))) __bf16 Bs[128 * LDT];

    int tid  = threadIdx.x;
    int lane = tid & 63;
    int wave = tid >> 6;
    int quad = lane >> 4;
    int l16  = lane & 15;
    int wm = (wave >> 1) * 64;
    int wn = (wave & 1) * 64;

    int mBase = blockIdx.y * 128;
    int nBase = blockIdx.x * 128;

    int trow  = tid >> 3;
    int tcol8 = (tid & 7) * 8;

    f32x4 acc[4][4] = {};

    for (int k0 = 0; k0 < K; k0 += 64) {
#pragma unroll
        for (int p = 0; p < 4; ++p) {
            int r = p * 32 + trow;
            const __bf16* ga = Ab + (long)(mBase + r) * lda + k0 + tcol8;
            *(uint4*)(&As[r * LDT + tcol8]) = *(const uint4*)ga;
            int gn = nBase + r; gn = gn < N ? gn : N - 1;
            const __bf16* gb = Bb + (long)gn * ldb + k0 + tcol8;
            *(uint4*)(&Bs[r * LDT + tcol8]) = *(const uint4*)gb;
        }
        __syncthreads();
#pragma unroll
        for (int ks = 0; ks < 2; ++ks) {
            int kof = ks * 32 + quad * 8;
            bf16x8 af[4], bfr[4];
#pragma unroll
            for (int mt = 0; mt < 4; ++mt)
                af[mt] = *(const bf16x8*)(&As[(wm + mt * 16 + l16) * LDT + kof]);
#pragma unroll
            for (int nt = 0; nt < 4; ++nt)
                bfr[nt] = *(const bf16x8*)(&Bs[(wn + nt * 16 + l16) * LDT + kof]);
#pragma unroll
            for (int mt = 0; mt < 4; ++mt)
#pragma unroll
                for (int nt = 0; nt < 4; ++nt)
                    acc[mt][nt] = __builtin_amdgcn_mfma_f32_16x16x32_bf16(
                        af[mt], bfr[nt], acc[mt][nt], 0, 0, 0);
        }
        __syncthreads();
    }

#pragma unroll
    for (int mt = 0; mt < 4; ++mt) {
#pragma unroll
        for (int nt = 0; nt < 4; ++nt) {
            int col = nBase + wn + nt * 16 + l16;
            if (col >= N) continue;
            int row0 = mBase + wm + mt * 16 + quad * 4;
            float bv = bias ? bias[col] : 0.f;
#pragma unroll
            for (int r = 0; r < 4; ++r) {
                long off = coff + (long)(row0 + r) * ldc + col;
                float v = acc[mt][nt][r] * scale + bv;
                if (resid) v += resid[off];
                if (relu) v = fmaxf(v, 0.f);
                if (outBf) ((__bf16*)Cp)[off] = (__bf16)v;
                else       ((float*)Cp)[off] = v;
            }
        }
    }
}

// =====================================================================
// ======  Windowed K=3 conv as MFMA GEMM, reg-prefetch dbuf  ==========
// =====================================================================
// R1-verified geometry: 8 waves, wave tile 32x64, block 128x128,
// 64-col K-chunks, LDT=72 padded LDS.  R5 adds next-chunk prefetch into
// NAMED uint4 registers (no arrays/lambdas -- R4's arrays were runtime-
// indexed inside lambdas and went to scratch: VGPR=44, WRITE_SIZE=394MB).
// __launch_bounds__(512,4) caps VGPR at 128 (need ~115; LDS already
// limits to 2 blocks/CU so nothing is lost).
#define CONV_LOAD(c0v)                                                   \
    do {                                                                 \
        la0 = *(const uint4*)(Ab + (long)offA0 + (c0v));                 \
        la1 = *(const uint4*)(Ab + (long)offA1 + (c0v));                 \
        if (tid < 16) la2 = *(const uint4*)(Ab + (long)offA2 + (c0v));   \
        lb0 = *(const uint4*)(W + (long)offB0 + (c0v));                  \
        lb1 = *(const uint4*)(W + (long)offB1 + (c0v));                  \
        lb2 = *(const uint4*)(W + (long)offB2 + (c0v));                  \
        lb3 = *(const uint4*)(W + (long)offB3 + (c0v));                  \
        lb4 = *(const uint4*)(W + (long)offB4 + (c0v));                  \
        lb5 = *(const uint4*)(W + (long)offB5 + (c0v));                  \
    } while (0)

#define CONV_STORE()                                                     \
    do {                                                                 \
        *(uint4*)(&As[sA0]) = la0;                                       \
        *(uint4*)(&As[sA1]) = la1;                                       \
        if (tid < 16) *(uint4*)(&As[sA2]) = la2;                         \
        *(uint4*)(&Bs[sB0]) = lb0;                                       \
        *(uint4*)(&Bs[sB1]) = lb1;                                       \
        *(uint4*)(&Bs[sB2]) = lb2;                                       \
        *(uint4*)(&Bs[sB3]) = lb3;                                       \
        *(uint4*)(&Bs[sB4]) = lb4;                                       \
        *(uint4*)(&Bs[sB5]) = lb5;                                       \
    } while (0)

__global__ __launch_bounds__(512, 4) void conv_mfma4(
    const __bf16* __restrict__ Apad, const __bf16* __restrict__ W,
    const float* __restrict__ bias, const float* __restrict__ resid,
    void* __restrict__ Cp, long ldc, long sC1,
    int T, int Tp2, int Cc, int O, int relu, int outBf)
{
    int z = blockIdx.z;
    int t0 = blockIdx.y * 128;
    int nBase = blockIdx.x * 128;
    const __bf16* Ab = Apad + ((long)z * Tp2 + t0) * Cc;   // LDS row r <-> pad row t0+r

    __shared__ __attribute__((aligned(16))) __bf16 As[130 * LDT];
    __shared__ __attribute__((aligned(16))) __bf16 Bs[3 * 128 * LDT];

    int tid  = threadIdx.x;
    int lane = tid & 63;
    int wave = tid >> 6;         // 0..7
    int quad = lane >> 4;
    int l16  = lane & 15;
    int wm = (wave >> 1) * 32;   // 0,32,64,96
    int wn = (wave & 1) * 64;    // 0,64

    long ldw = 3L * Cc;

    // ---- per-thread staging indices (hoisted once) ----
    // A: u = tid + i*512 (i=0,1,2; i=2 only tid<16): r=u>>3, c=(u&7)*8
    int rA0 = tid >> 3,            cA0 = (tid & 7) * 8;
    int rA1 = (tid + 512) >> 3,    cA1 = cA0;            // (u&7) unchanged by +512
    int rA2 = (tid + 1024) >> 3,   cA2 = cA0;
    int offA0 = rA0 * Cc + cA0;
    int offA1 = rA1 * Cc + cA1;
    int offA2 = rA2 * Cc + cA2;
    int sA0 = rA0 * LDT + cA0;
    int sA1 = rA1 * LDT + cA1;
    int sA2 = rA2 * LDT + cA2;
    // B: u = tid + i*512 (i=0..5): kk=i>>1 pattern holds since 512*2=1024:
    //    kk=u>>10, rr=(u>>3)&127, cc=(u&7)*8
    int rB0 = (tid >> 3) & 127,          cB0 = (tid & 7) * 8;
    int rB1 = ((tid + 512) >> 3) & 127;
    int offB0 = (nBase + rB0) * (int)ldw + 0 * Cc + cB0;
    int offB1 = (nBase + rB1) * (int)ldw + 0 * Cc + cB0;
    int offB2 = (nBase + rB0) * (int)ldw + 1 * Cc + cB0;
    int offB3 = (nBase + rB1) * (int)ldw + 1 * Cc + cB0;
    int offB4 = (nBase + rB0) * (int)ldw + 2 * Cc + cB0;
    int offB5 = (nBase + rB1) * (int)ldw + 2 * Cc + cB0;
    int sB0 = 0 * 128 * LDT + rB0 * LDT + cB0;
    int sB1 = 0 * 128 * LDT + rB1 * LDT + cB0;
    int sB2 = 1 * 128 * LDT + rB0 * LDT + cB0;
    int sB3 = 1 * 128 * LDT + rB1 * LDT + cB0;
    int sB4 = 2 * 128 * LDT + rB0 * LDT + cB0;
    int sB5 = 2 * 128 * LDT + rB1 * LDT + cB0;

    uint4 la0, la1, la2, lb0, lb1, lb2, lb3, lb4, lb5;

    f32x4 acc[2][4] = {};

    CONV_LOAD(0);

    for (int c0 = 0; c0 < Cc; c0 += 64) {
        __syncthreads();              // previous chunk's readers done
        CONV_STORE();
        __syncthreads();              // LDS ready
        if (c0 + 64 < Cc)
            CONV_LOAD(c0 + 64);       // latency hides under MFMA phase below
#pragma unroll
        for (int kk = 0; kk < 3; ++kk) {
#pragma unroll
            for (int ks = 0; ks < 2; ++ks) {
                int kof = ks * 32 + quad * 8;
                bf16x8 a0 = *(const bf16x8*)(&As[(wm + l16 + kk) * LDT + kof]);
                bf16x8 a1 = *(const bf16x8*)(&As[(wm + 16 + l16 + kk) * LDT + kof]);
                bf16x8 b0 = *(const bf16x8*)(&Bs[kk * 128 * LDT + (wn + l16) * LDT + kof]);
                bf16x8 b1 = *(const bf16x8*)(&Bs[kk * 128 * LDT + (wn + 16 + l16) * LDT + kof]);
                bf16x8 b2 = *(const bf16x8*)(&Bs[kk * 128 * LDT + (wn + 32 + l16) * LDT + kof]);
                bf16x8 b3 = *(const bf16x8*)(&Bs[kk * 128 * LDT + (wn + 48 + l16) * LDT + kof]);
                acc[0][0] = __builtin_amdgcn_mfma_f32_16x16x32_bf16(a0, b0, acc[0][0], 0, 0, 0);
                acc[0][1] = __builtin_amdgcn_mfma_f32_16x16x32_bf16(a0, b1, acc[0][1], 0, 0, 0);
                acc[0][2] = __builtin_amdgcn_mfma_f32_16x16x32_bf16(a0, b2, acc[0][2], 0, 0, 0);
                acc[0][3] = __builtin_amdgcn_mfma_f32_16x16x32_bf16(a0, b3, acc[0][3], 0, 0, 0);
                acc[1][0] = __builtin_amdgcn_mfma_f32_16x16x32_bf16(a1, b0, acc[1][0], 0, 0, 0);
                acc[1][1] = __builtin_amdgcn_mfma_f32_16x16x32_bf16(a1, b1, acc[1][1], 0, 0, 0);
                acc[1][2] = __builtin_amdgcn_mfma_f32_16x16x32_bf16(a1, b2, acc[1][2], 0, 0, 0);
                acc[1][3] = __builtin_amdgcn_mfma_f32_16x16x32_bf16(a1, b3, acc[1][3], 0, 0, 0);
            }
        }
    }

    // epilogue: C/D layout col=l16, row=quad*4+r ; local row = wm + mt*16 + quad*4 + r
#pragma unroll
    for (int mt = 0; mt < 2; ++mt) {
#pragma unroll
        for (int nt = 0; nt < 4; ++nt) {
            int col = nBase + wn + nt * 16 + l16;
            int trow = t0 + wm + mt * 16 + quad * 4;
            float bv = bias[col];
#pragma unroll
            for (int r = 0; r < 4; ++r) {
                long off = (long)z * sC1 + (long)(trow + r) * ldc + col;
                float v = acc[mt][nt][r] + bv;
                if (resid) v += resid[off];
                if (relu) v = fmaxf(v, 0.f);
                if (outBf) ((__bf16*)Cp)[off] = (__bf16)v;
                else       ((float*)Cp)[off] = v;
            }
        }
    }
}

// =====================================================================
// ======  Fused flash attention (QK^T -> softmax -> PV), DH=192  ======
// =====================================================================
__global__ __launch_bounds__(512) void flash_attn(
    const __bf16* __restrict__ qkv, __bf16* __restrict__ o, int T, float scl)
{
    int z = blockIdx.y;
    int b = z >> 1, h = z & 1;
    const __bf16* base = qkv + (long)b * T * 3 * CD + h * CDH;
    int qBase = blockIdx.x * 128;

    __shared__ __attribute__((aligned(16))) __bf16 Qs[128][200];
    __shared__ __attribute__((aligned(16))) __bf16 Ks[64][200];
    __shared__ __attribute__((aligned(16))) __bf16 Vt[192][72];
    __shared__ __attribute__((aligned(16))) __bf16 Ps[128][72];

    int tid  = threadIdx.x;
    int lane = tid & 63;
    int wave = tid >> 6;
    int quad = lane >> 4;
    int l16  = lane & 15;
    int wq   = wave * 16;

#pragma unroll
    for (int i = 0; i < 6; ++i) {
        int u = tid + i * 512;
        int r = u / 24, c = (u % 24) * 8;
        *(uint4*)(&Qs[r][c]) = *(const uint4*)(base + (long)(qBase + r) * 3 * CD + c);
    }

    f32x4 oacc[12];
#pragma unroll
    for (int j = 0; j < 12; ++j) oacc[j] = (f32x4){0.f, 0.f, 0.f, 0.f};
    float mrow[4], lrow[4];
#pragma unroll
    for (int r = 0; r < 4; ++r) { mrow[r] = -3.0e38f; lrow[r] = 0.f; }

    for (int kv0 = 0; kv0 < T; kv0 += 64) {
        __syncthreads();
#pragma unroll
        for (int i = 0; i < 3; ++i) {
            int u = tid + i * 512;
            int r = u / 24, c = (u % 24) * 8;
            *(uint4*)(&Ks[r][c]) = *(const uint4*)(base + CD + (long)(kv0 + r) * 3 * CD + c);
        }
        // V transpose staging: r = u&63 (kv row), c = (u>>6)*8 (d-block) ->
        // per write-instruction the 64 lanes write 64 consecutive Vt columns
        // (128 contiguous B = all 32 banks, <=2-way).  (R1 fix: was ~24-way.)
#pragma unroll
        for (int i = 0; i < 3; ++i) {
            int u = tid + i * 512;
            int r = u & 63, c = (u >> 6) * 8;
            uint4 pkt = *(const uint4*)(base + 2 * CD + (long)(kv0 + r) * 3 * CD + c);
            const __bf16* v8 = (const __bf16*)&pkt;
#pragma unroll
            for (int j = 0; j < 8; ++j) Vt[c + j][r] = v8[j];
        }
        __syncthreads();

        f32x4 s[4];
#pragma unroll
        for (int nt = 0; nt < 4; ++nt) s[nt] = (f32x4){0.f, 0.f, 0.f, 0.f};
#pragma unroll
        for (int ks = 0; ks < 6; ++ks) {
            bf16x8 aq = *(const bf16x8*)(&Qs[wq + l16][ks * 32 + quad * 8]);
#pragma unroll
            for (int nt = 0; nt < 4; ++nt) {
                bf16x8 bk = *(const bf16x8*)(&Ks[nt * 16 + l16][ks * 32 + quad * 8]);
                s[nt] = __builtin_amdgcn_mfma_f32_16x16x32_bf16(aq, bk, s[nt], 0, 0, 0);
            }
        }
        float alpha[4];
#pragma unroll
        for (int r = 0; r < 4; ++r) {
            float mx = -3.0e38f;
#pragma unroll
            for (int nt = 0; nt < 4; ++nt) {
                s[nt][r] *= scl;
                mx = fmaxf(mx, s[nt][r]);
            }
            mx = fmaxf(mx, __shfl_xor(mx, 1));
            mx = fmaxf(mx, __shfl_xor(mx, 2));
            mx = fmaxf(mx, __shfl_xor(mx, 4));
            mx = fmaxf(mx, __shfl_xor(mx, 8));
            float mnew = fmaxf(mrow[r], mx);
            alpha[r] = __expf(mrow[r] - mnew);
            mrow[r] = mnew;
            float rs = 0.f;
#pragma unroll
            for (int nt = 0; nt < 4; ++nt) {
                float e = __expf(s[nt][r] - mnew);
                s[nt][r] = e;
                rs += e;
            }
            rs += __shfl_xor(rs, 1);
            rs += __shfl_xor(rs, 2);
            rs += __shfl_xor(rs, 4);
            rs += __shfl_xor(rs, 8);
            lrow[r] = lrow[r] * alpha[r] + rs;
        }
#pragma unroll
        for (int r = 0; r < 4; ++r)
#pragma unroll
            for (int nt = 0; nt < 4; ++nt)
                Ps[wq + quad * 4 + r][nt * 16 + l16] = (__bf16)s[nt][r];
#pragma unroll
        for (int j = 0; j < 12; ++j)
#pragma unroll
            for (int r = 0; r < 4; ++r) oacc[j][r] *= alpha[r];
#pragma unroll
        for (int ks2 = 0; ks2 < 2; ++ks2) {
            bf16x8 ap = *(const bf16x8*)(&Ps[wq + l16][ks2 * 32 + quad * 8]);
#pragma unroll
            for (int nt = 0; nt < 12; ++nt) {
                bf16x8 bv = *(const bf16x8*)(&Vt[nt * 16 + l16][ks2 * 32 + quad * 8]);
                oacc[nt] = __builtin_amdgcn_mfma_f32_16x16x32_bf16(ap, bv, oacc[nt], 0, 0, 0);
            }
        }
    }

    __bf16* ob = o + ((long)b * T + qBase + wq + quad * 4) * CD + h * CDH + l16;
#pragma unroll
    for (int r = 0; r < 4; ++r) {
        float inv = 1.0f / lrow[r];
#pragma unroll
        for (int nt = 0; nt < 12; ++nt)
            ob[(long)r * CD + nt * 16] = (__bf16)(oacc[nt][r] * inv);
    }
}

// ---- LN: out32 = LN(a)*g+be ; bf16 padded copy ----
__global__ __launch_bounds__(CD) void ln_res(const float* __restrict__ a,
    const float* __restrict__ g, const float* __restrict__ be,
    float* __restrict__ out32, __bf16* __restrict__ outbf, int Tlog2)
{
    long r = blockIdx.x;
    int d = threadIdx.x;
    float v = a[r * CD + d];
    float s1 = v, s2 = v * v;
#pragma unroll
    for (int off = 32; off > 0; off >>= 1) {
        s1 += __shfl_down(s1, off);
        s2 += __shfl_down(s2, off);
    }
    __shared__ float sh1[CD / 64], sh2[CD / 64];
    int wv = d >> 6, ln = d & 63;
    if (ln == 0) { sh1[wv] = s1; sh2[wv] = s2; }
    __syncthreads();
    if (d == 0) {
        float t1 = 0.f, t2 = 0.f;
        for (int i = 0; i < CD / 64; ++i) { t1 += sh1[i]; t2 += sh2[i]; }
        sh1[0] = t1; sh2[0] = t2;
    }
    __syncthreads();
    float mean = sh1[0] * (1.0f / CD);
    float var  = sh2[0] * (1.0f / CD) - mean * mean;
    float res = (v - mean) * rsqrtf(var + 1e-5f) * g[d] + be[d];
    out32[r * CD + d] = res;
    int T = 1 << Tlog2;
    long bb = r >> Tlog2; int t = (int)(r & (T - 1));
    outbf[(bb * (T + 2) + t + 1) * CD + d] = (__bf16)res;
}

__global__ __launch_bounds__(CD) void f32_to_padbf16(const float* __restrict__ in,
    __bf16* __restrict__ out, int Tlog2)
{
    long r = blockIdx.x;
    int d = threadIdx.x;
    int T = 1 << Tlog2;
    long b = r >> Tlog2; int t = (int)(r & (T - 1));
    out[(b * (T + 2) + t + 1) * CD + d] = (__bf16)in[r * CD + d];
}

__global__ void zero_pads(__bf16* __restrict__ p, int Tp2, int C)
{
    int b = blockIdx.x >> 1;
    int which = blockIdx.x & 1;
    long row = (long)b * Tp2 + (which ? Tp2 - 1 : 0);
    for (int c = threadIdx.x; c < C; c += blockDim.x) p[row * C + c] = (__bf16)0.f;
}

__global__ __launch_bounds__(256) void tr_f32_bf16(const float* __restrict__ in,
    __bf16* __restrict__ out, int R, int C)
{
    __shared__ float t[32][33];
    int c0 = blockIdx.x * 32, r0 = blockIdx.y * 32;
    int tx = threadIdx.x & 31, ty = threadIdx.x >> 5;
#pragma unroll
    for (int i = 0; i < 4; ++i) {
        int rr = ty * 4 + i;
        int r = r0 + rr, c = c0 + tx;
        if (r < R && c < C) t[rr][tx] = in[(long)r * C + c];
    }
    __syncthreads();
#pragma unroll
    for (int i = 0; i < 4; ++i) {
        int cc = ty * 4 + i;
        int c = c0 + cc, r = r0 + tx;
        if (c < C && r < R) out[(long)c * R + r] = (__bf16)t[tx][cc];
    }
}

__global__ void convw_bf16(const float* __restrict__ w, __bf16* __restrict__ wt,
                           int O, int Cc)
{
    long total = (long)O * 3 * Cc;
    int KC = 3 * Cc;
    for (long i = (long)blockIdx.x * blockDim.x + threadIdx.x; i < total;
         i += (long)gridDim.x * blockDim.x) {
        int j = (int)(i % KC); long o = i / KC;
        int kk = j / Cc, c = j % Cc;
        wt[i] = (__bf16)w[(o * Cc + c) * 3 + kk];
    }
}

__global__ __launch_bounds__(CD) void embed_pe_kernel(const int* __restrict__ x,
    const float* __restrict__ emb, float* __restrict__ h)
{
    int bs = blockIdx.x;
    int d  = threadIdx.x;
    int s  = bs & (CS - 1);
    int tok = x[bs];
    int i = d >> 1;
    float ang = (float)s * powf(10000.0f, -2.0f * (float)i / (float)CD);
    float pe = (d & 1) ? cosf(ang) : sinf(ang);
    h[(size_t)bs * CD + d] = emb[(size_t)tok * CD + d] + pe;
}

__global__ __launch_bounds__(CS) void lenreg_kernel(const int* __restrict__ y,
    int* __restrict__ idx, int* __restrict__ totals)
{
    __shared__ int ends[CS];
    int b = blockIdx.x, tid = threadIdx.x;
    if (tid == 0) {
        int acc = 0;
        for (int s = 0; s < CS; ++s) { acc += y[b * CS + s]; ends[s] = acc; }
    }
    __syncthreads();
    for (int t = tid; t < CLOUT; t += CS) idx[b * CLOUT + t] = CS - 1;
    if (tid == 0) totals[b] = ends[CS - 1];
    __syncthreads();
    int st = (tid == 0) ? 0 : ends[tid - 1];
    int en = ends[tid];
    for (int t = st; t < en; ++t) idx[b * CLOUT + t] = tid;
}

__global__ __launch_bounds__(CD) void gather_dual(const float* __restrict__ hph,
    const int* __restrict__ idx, const int* __restrict__ tot,
    float* __restrict__ h32, __bf16* __restrict__ hbf, int chunkBase)
{
    int rl = blockIdx.x;
    int rg = chunkBase + rl;
    int b = rg >> 10, t = rg & (CLOUT - 1);
    int d = threadIdx.x;
    int src = idx[rg];
    float v = (t < tot[b]) ? hph[((long)b * CS + src) * CD + d] : 0.f;
    h32[(long)rl * CD + d] = v;
    long bl = rl >> 10; int tl = rl & (CLOUT - 1);
    hbf[(bl * (CLOUT + 2) + tl + 1) * CD + d] = (__bf16)v;
}

// =====================================================================
// ===============  bf16 path driver  ==================================
// =====================================================================

static inline void mm(hipStream_t st, const __bf16* A, long lda, long sA1, long sA2,
    const __bf16* Bt, long ldb, long sB1, long sB2, const float* bias,
    const float* resid, void* C, long ldc, long sC1, long sC2, int M, int N, int K,
    int nz, int zdiv, int relu, int outBf, float scale)
{
    dim3 g((N + 127) / 128, M / 128, nz), b(256, 1, 1);
    hipLaunchKernelGGL(mm_bf16, g, b, 0, st, A, lda, sA1, sA2, Bt, ldb, sB1, sB2,
                       bias, resid, C, ldc, sC1, sC2, M, N, K, zdiv, relu, outBf, scale);
}

struct Scr {
    float *h32, *x32, *tmp32;
    __bf16 *hbf, *xbf, *qkv, *c1p, *o;
};

static size_t scr_layout(char* base, int NB, int T, Scr* s)
{
    auto align = [](size_t v) { return (v + 255) & ~(size_t)255; };
    size_t off = 0;
    long Tp2 = T + 2;
    if (s) s->h32 = (float*)(base + off);
    off = align(off + (size_t)NB * T * CD * 4);
    if (s) s->x32 = (float*)(base + off);
    off = align(off + (size_t)NB * T * CD * 4);
    if (s) s->tmp32 = (float*)(base + off);
    off = align(off + (size_t)NB * T * CD * 4);
    if (s) s->hbf = (__bf16*)(base + off);
    off = align(off + (size_t)NB * Tp2 * CD * 2);
    if (s) s->xbf = (__bf16*)(base + off);
    off = align(off + (size_t)NB * Tp2 * CD * 2);
    if (s) s->qkv = (__bf16*)(base + off);
    off = align(off + (size_t)NB * T * 3 * CD * 2);
    if (s) s->c1p = (__bf16*)(base + off);
    off = align(off + (size_t)NB * Tp2 * CDF * 2);
    if (s) s->o = (__bf16*)(base + off);
    off = align(off + (size_t)NB * T * CD * 2);
    return off;
}

// per-layer bf16 weight offsets (elements)
constexpr long W_QKV = 0;
constexpr long W_OUT = 442368;
constexpr long W_C1  = 589824;
constexpr long W_C2  = 2359296;
constexpr long WLAYER = 4128768;
constexpr long WSTACK = 6 * WLAYER;
constexpr long WTOT   = WSTACK + 30720;

static void convert_stack_weights(hipStream_t st, __bf16* wbuf,
    const float* qkv_w, const float* out_w, const float* c1w, const float* c2w)
{
    for (int l = 0; l < CL; ++l) {
        __bf16* wl = wbuf + (long)l * WLAYER;
        hipLaunchKernelGGL(tr_f32_bf16, dim3(36, 12), dim3(256), 0, st,
                           qkv_w + (long)l * CD * 3 * CD, wl + W_QKV, CD, 3 * CD);
        hipLaunchKernelGGL(tr_f32_bf16, dim3(12, 12), dim3(256), 0, st,
                           out_w + (long)l * CD * CD, wl + W_OUT, CD, CD);
        hipLaunchKernelGGL(convw_bf16, dim3(2048), dim3(256), 0, st,
                           c1w + (long)l * CDF * CD * 3, wl + W_C1, CDF, CD);
        hipLaunchKernelGGL(convw_bf16, dim3(2048), dim3(256), 0, st,
                           c2w + (long)l * CD * CDF * 3, wl + W_C2, CD, CDF);
    }
}

static void fft_block_bf16(hipStream_t st, const Scr& S, int NBc, int T, int tlog2,
    float* h32, const __bf16* wl,
    const float* qkv_b, const float* out_b,
    const float* g1, const float* b1, const float* c1b, const float* c2b,
    const float* g2, const float* b2)
{
    const int M = NBc * T;
    const long Tp2 = T + 2;
    const float scl = 1.0f / sqrtf((float)CDH);

    // qkv = h @ Wqkv + b
    mm(st, S.hbf + CD, CD, Tp2 * CD, 0, wl + W_QKV, CD, 0, 0, qkv_b, nullptr,
       S.qkv, 3 * CD, (long)T * 3 * CD, 0, T, 3 * CD, CD, NBc, 1, 0, 1, 1.f);

    // fused attention
    hipLaunchKernelGGL(flash_attn, dim3(T / 128, NBc * CH), dim3(512), 0, st,
                       S.qkv, S.o, T, scl);

    // tmp = o @ Wout + b + h (residual fused)
    mm(st, S.o, CD, 0, 0, wl + W_OUT, CD, 0, 0, out_b, h32,
       S.tmp32, CD, 0, 0, M, CD, CD, 1, 1, 0, 0, 1.f);

    // x = LN(tmp)
    hipLaunchKernelGGL(ln_res, dim3(M), dim3(CD), 0, st,
                       S.tmp32, g1, b1, S.x32, S.xbf, tlog2);

    // conv1: relu(conv(x)) -> c1p rows 1..T (bf16); reg-prefetch conv
    hipLaunchKernelGGL(conv_mfma4, dim3(CDF / 128, T / 128, NBc), dim3(512), 0, st,
                       S.xbf, wl + W_C1, c1b, nullptr,
                       (void*)(S.c1p + CDF), (long)CDF, Tp2 * CDF,
                       T, (int)Tp2, CD, CDF, 1, 1);

    // conv2 + resid -> tmp32 (fp32)
    hipLaunchKernelGGL(conv_mfma4, dim3(CD / 128, T / 128, NBc), dim3(512), 0, st,
                       S.c1p, wl + W_C2, c2b, S.x32,
                       S.tmp32, (long)CD, (long)T * CD,
                       T, (int)Tp2, CDF, CD, 0, 0);

    // h = LN(tmp)
    hipLaunchKernelGGL(ln_res, dim3(M), dim3(CD), 0, st,
                       S.tmp32, g2, b2, h32, S.hbf, tlog2);
}

extern "C" void kernel_launch(void* const* d_in, const int* in_sizes, int n_in,
                              void* d_out, int out_size, void* d_ws, size_t ws_size,
                              hipStream_t stream)
{
    (void)in_sizes; (void)out_size;

    const int* x = (const int*)d_in[0];
    const int* y = (const int*)d_in[1];
    const float* P[40];
    for (int i = 0; i < n_in && i < 40; ++i) P[i] = (const float*)d_in[i];

    size_t wbufB  = ((size_t)WTOT * 2 + 255) & ~(size_t)255;
    size_t hphB   = ((size_t)CB * CS * CD * 4 + 255) & ~(size_t)255;
    size_t idxB   = (((size_t)CB * CLOUT + CB) * 4 + 255) & ~(size_t)255;
    size_t fixedB = wbufB + hphB + idxB;

    size_t scrB = (ws_size > fixedB) ? (ws_size - fixedB) : 0;

    int NBmel = 1;
    for (int cand = 16; cand >= 1; cand >>= 1)
        if (scr_layout(nullptr, cand, CLOUT, nullptr) <= scrB) { NBmel = cand; break; }

    int NBph = 1;
    for (int cand = 16; cand >= 1; cand >>= 1)
        if (scr_layout(nullptr, cand, CS, nullptr) <= scrB) { NBph = cand; break; }

    char* base = (char*)d_ws;
    __bf16* wbuf = (__bf16*)base;
    float*  hPh  = (float*)(base + wbufB);
    int*    idxb = (int*)(base + wbufB + hphB);
    int*    totb = idxb + (long)CB * CLOUT;
    char*   scrbase = base + fixedB;

    // ================= phoneme encoder =================
    convert_stack_weights(stream, wbuf, P[3], P[5], P[9], P[11]);

    Scr Sp; scr_layout(scrbase, NBph, CS, &Sp);
    hipLaunchKernelGGL(zero_pads, dim3(NBph * 2), dim3(256), 0, stream, Sp.hbf, CS + 2, CD);
    hipLaunchKernelGGL(zero_pads, dim3(NBph * 2), dim3(256), 0, stream, Sp.xbf, CS + 2, CD);
    hipLaunchKernelGGL(zero_pads, dim3(NBph * 2), dim3(256), 0, stream, Sp.c1p, CS + 2, CDF);

    hipLaunchKernelGGL(embed_pe_kernel, dim3(CB * CS), dim3(CD), 0, stream, x, P[2], hPh);

    for (int c = 0; c < CB / NBph; ++c) {
        float* hch = hPh + (long)c * NBph * CS * CD;
        hipLaunchKernelGGL(f32_to_padbf16, dim3(NBph * CS), dim3(CD), 0, stream,
                           hch, Sp.hbf, 7);
        for (int l = 0; l < CL; ++l)
            fft_block_bf16(stream, Sp, NBph, CS, 7, hch, wbuf + (long)l * WLAYER,
                           P[4] + (long)l * 3 * CD, P[6] + (long)l * CD,
                           P[7] + (long)l * CD, P[8] + (long)l * CD,
                           P[10] + (long)l * CDF, P[12] + (long)l * CD,
                           P[13] + (long)l * CD, P[14] + (long)l * CD);
    }

    // ================= length regulation =================
    hipLaunchKernelGGL(lenreg_kernel, dim3(CB), dim3(CS), 0, stream, y, idxb, totb);

    // ================= mel decoder =================
    convert_stack_weights(stream, wbuf, P[15], P[17], P[21], P[23]);
    hipLaunchKernelGGL(tr_f32_bf16, dim3(3, 12), dim3(256), 0, stream,
                       P[37], wbuf + WSTACK, CD, CNM);

    Scr Sm; scr_layout(scrbase, NBmel, CLOUT, &Sm);
    hipLaunchKernelGGL(zero_pads, dim3(NBmel * 2), dim3(256), 0, stream, Sm.hbf, CLOUT + 2, CD);
    hipLaunchKernelGGL(zero_pads, dim3(NBmel * 2), dim3(256), 0, stream, Sm.xbf, CLOUT + 2, CD);
    hipLaunchKernelGGL(zero_pads, dim3(NBmel * 2), dim3(256), 0, stream, Sm.c1p, CLOUT + 2, CDF);

    for (int c = 0; c < CB / NBmel; ++c) {
        hipLaunchKernelGGL(gather_dual, dim3(NBmel * CLOUT), dim3(CD), 0, stream,
                           hPh, idxb, totb, Sm.h32, Sm.hbf, c * NBmel * CLOUT);
        for (int l = 0; l < CL; ++l)
            fft_block_bf16(stream, Sm, NBmel, CLOUT, 10, Sm.h32, wbuf + (long)l * WLAYER,
                           P[16] + (long)l * 3 * CD, P[18] + (long)l * CD,
                           P[19] + (long)l * CD, P[20] + (long)l * CD,
                           P[22] + (long)l * CDF, P[24] + (long)l * CD,
                           P[25] + (long)l * CD, P[26] + (long)l * CD);
        // final projection for this chunk
        mm(stream, Sm.hbf + CD, CD, (long)(CLOUT + 2) * CD, 0,
           wbuf + WSTACK, CD, 0, 0, P[38], nullptr,
           (float*)d_out + (long)c * NBmel * CLOUT * CNM, CNM, (long)CLOUT * CNM, 0,
           CLOUT, CNM, CD, NBmel, 1, 0, 0, 1.f);
    }
}

// Round 6
// 3503.407 us; speedup vs baseline: 1.7229x; 1.0010x over previous
//
#include <hip/hip_runtime.h>
#include <cstddef>
#include <cmath>

// ---------------- problem constants ----------------
constexpr int CB  = 16;
constexpr int CS  = 128;
constexpr int CD  = 384;
constexpr int CDF = 1536;
constexpr int CH  = 2;
constexpr int CL  = 6;
constexpr int CNM = 80;
constexpr int CLOUT = 1024;
constexpr int CDH = 192;

typedef __bf16 bf16x8 __attribute__((ext_vector_type(8)));
typedef float  f32x4  __attribute__((ext_vector_type(4)));

// =====================================================================
// ======  bf16 MFMA GEMM (verified padded-LDS staging)  ===============
// =====================================================================
constexpr int LDT = 72;
__global__ __launch_bounds__(256) void mm_bf16(
    const __bf16* __restrict__ A, long lda, long sA1, long sA2,
    const __bf16* __restrict__ Bt, long ldb, long sB1, long sB2,
    const float* __restrict__ bias, const float* __restrict__ resid,
    void* __restrict__ Cp, long ldc, long sC1, long sC2,
    int M, int N, int K, int zdiv, int relu, int outBf, float scale)
{
    int z = blockIdx.z;
    int zb = z / zdiv, zh = z % zdiv;
    const __bf16* Ab = A  + (long)zb * sA1 + (long)zh * sA2;
    const __bf16* Bb = Bt + (long)zb * sB1 + (long)zh * sB2;
    long coff = (long)zb * sC1 + (long)zh * sC2;

    __shared__ __attribute__((aligned(16))) __bf16 As[128 * LDT];
    __shared__ __attribute__((aligned(16))) __bf16 Bs[128 * LDT];

    int tid  = threadIdx.x;
    int lane = tid & 63;
    int wave = tid >> 6;
    int quad = lane >> 4;
    int l16  = lane & 15;
    int wm = (wave >> 1) * 64;
    int wn = (wave & 1) * 64;

    int mBase = blockIdx.y * 128;
    int nBase = blockIdx.x * 128;

    int trow  = tid >> 3;
    int tcol8 = (tid & 7) * 8;

    f32x4 acc[4][4] = {};

    for (int k0 = 0; k0 < K; k0 += 64) {
#pragma unroll
        for (int p = 0; p < 4; ++p) {
            int r = p * 32 + trow;
            const __bf16* ga = Ab + (long)(mBase + r) * lda + k0 + tcol8;
            *(uint4*)(&As[r * LDT + tcol8]) = *(const uint4*)ga;
            int gn = nBase + r; gn = gn < N ? gn : N - 1;
            const __bf16* gb = Bb + (long)gn * ldb + k0 + tcol8;
            *(uint4*)(&Bs[r * LDT + tcol8]) = *(const uint4*)gb;
        }
        __syncthreads();
#pragma unroll
        for (int ks = 0; ks < 2; ++ks) {
            int kof = ks * 32 + quad * 8;
            bf16x8 af[4], bfr[4];
#pragma unroll
            for (int mt = 0; mt < 4; ++mt)
                af[mt] = *(const bf16x8*)(&As[(wm + mt * 16 + l16) * LDT + kof]);
#pragma unroll
            for (int nt = 0; nt < 4; ++nt)
                bfr[nt] = *(const bf16x8*)(&Bs[(wn + nt * 16 + l16) * LDT + kof]);
#pragma unroll
            for (int mt = 0; mt < 4; ++mt)
#pragma unroll
                for (int nt = 0; nt < 4; ++nt)
                    acc[mt][nt] = __builtin_amdgcn_mfma_f32_16x16x32_bf16(
                        af[mt], bfr[nt], acc[mt][nt], 0, 0, 0);
        }
        __syncthreads();
    }

#pragma unroll
    for (int mt = 0; mt < 4; ++mt) {
#pragma unroll
        for (int nt = 0; nt < 4; ++nt) {
            int col = nBase + wn + nt * 16 + l16;
            if (col >= N) continue;
            int row0 = mBase + wm + mt * 16 + quad * 4;
            float bv = bias ? bias[col] : 0.f;
#pragma unroll
            for (int r = 0; r < 4; ++r) {
                long off = coff + (long)(row0 + r) * ldc + col;
                float v = acc[mt][nt][r] * scale + bv;
                if (resid) v += resid[off];
                if (relu) v = fmaxf(v, 0.f);
                if (outBf) ((__bf16*)Cp)[off] = (__bf16)v;
                else       ((float*)Cp)[off] = v;
            }
        }
    }
}

// =====================================================================
// ======  Windowed K=3 conv as MFMA GEMM, reg-prefetch dbuf  ==========
// =====================================================================
// R1-verified geometry: 8 waves, wave tile 32x64, block 128x128,
// 64-col K-chunks, LDT=72 padded LDS.  Named-register prefetch (R5).
// R6: R5's VGPR=60 proved the compiler SANK the prefetch loads down to
// the CONV_STORE site (live range collapsed; latency exposed again).
// Fix per skill rule #18 family: __builtin_amdgcn_sched_barrier(0)
// immediately after CONV_LOAD pins the 9 global loads ABOVE the MFMA
// region, so they stay in flight under compute.  Tell: VGPR >= ~96.
#define CONV_LOAD(c0v)                                                   \
    do {                                                                 \
        la0 = *(const uint4*)(Ab + (long)offA0 + (c0v));                 \
        la1 = *(const uint4*)(Ab + (long)offA1 + (c0v));                 \
        if (tid < 16) la2 = *(const uint4*)(Ab + (long)offA2 + (c0v));   \
        lb0 = *(const uint4*)(W + (long)offB0 + (c0v));                  \
        lb1 = *(const uint4*)(W + (long)offB1 + (c0v));                  \
        lb2 = *(const uint4*)(W + (long)offB2 + (c0v));                  \
        lb3 = *(const uint4*)(W + (long)offB3 + (c0v));                  \
        lb4 = *(const uint4*)(W + (long)offB4 + (c0v));                  \
        lb5 = *(const uint4*)(W + (long)offB5 + (c0v));                  \
    } while (0)

#define CONV_STORE()                                                     \
    do {                                                                 \
        *(uint4*)(&As[sA0]) = la0;                                       \
        *(uint4*)(&As[sA1]) = la1;                                       \
        if (tid < 16) *(uint4*)(&As[sA2]) = la2;                         \
        *(uint4*)(&Bs[sB0]) = lb0;                                       \
        *(uint4*)(&Bs[sB1]) = lb1;                                       \
        *(uint4*)(&Bs[sB2]) = lb2;                                       \
        *(uint4*)(&Bs[sB3]) = lb3;                                       \
        *(uint4*)(&Bs[sB4]) = lb4;                                       \
        *(uint4*)(&Bs[sB5]) = lb5;                                       \
    } while (0)

__global__ __launch_bounds__(512, 4) void conv_mfma4(
    const __bf16* __restrict__ Apad, const __bf16* __restrict__ W,
    const float* __restrict__ bias, const float* __restrict__ resid,
    void* __restrict__ Cp, long ldc, long sC1,
    int T, int Tp2, int Cc, int O, int relu, int outBf)
{
    int z = blockIdx.z;
    int t0 = blockIdx.y * 128;
    int nBase = blockIdx.x * 128;
    const __bf16* Ab = Apad + ((long)z * Tp2 + t0) * Cc;   // LDS row r <-> pad row t0+r

    __shared__ __attribute__((aligned(16))) __bf16 As[130 * LDT];
    __shared__ __attribute__((aligned(16))) __bf16 Bs[3 * 128 * LDT];

    int tid  = threadIdx.x;
    int lane = tid & 63;
    int wave = tid >> 6;         // 0..7
    int quad = lane >> 4;
    int l16  = lane & 15;
    int wm = (wave >> 1) * 32;   // 0,32,64,96
    int wn = (wave & 1) * 64;    // 0,64

    long ldw = 3L * Cc;

    // ---- per-thread staging indices (hoisted once) ----
    // A: u = tid + i*512 (i=0,1,2; i=2 only tid<16): r=u>>3, c=(u&7)*8
    int rA0 = tid >> 3,            cA0 = (tid & 7) * 8;
    int rA1 = (tid + 512) >> 3,    cA1 = cA0;            // (u&7) unchanged by +512
    int rA2 = (tid + 1024) >> 3,   cA2 = cA0;
    int offA0 = rA0 * Cc + cA0;
    int offA1 = rA1 * Cc + cA1;
    int offA2 = rA2 * Cc + cA2;
    int sA0 = rA0 * LDT + cA0;
    int sA1 = rA1 * LDT + cA1;
    int sA2 = rA2 * LDT + cA2;
    // B: u = tid + i*512 (i=0..5): kk=u>>10, rr=(u>>3)&127, cc=(u&7)*8
    int rB0 = (tid >> 3) & 127,          cB0 = (tid & 7) * 8;
    int rB1 = ((tid + 512) >> 3) & 127;
    int offB0 = (nBase + rB0) * (int)ldw + 0 * Cc + cB0;
    int offB1 = (nBase + rB1) * (int)ldw + 0 * Cc + cB0;
    int offB2 = (nBase + rB0) * (int)ldw + 1 * Cc + cB0;
    int offB3 = (nBase + rB1) * (int)ldw + 1 * Cc + cB0;
    int offB4 = (nBase + rB0) * (int)ldw + 2 * Cc + cB0;
    int offB5 = (nBase + rB1) * (int)ldw + 2 * Cc + cB0;
    int sB0 = 0 * 128 * LDT + rB0 * LDT + cB0;
    int sB1 = 0 * 128 * LDT + rB1 * LDT + cB0;
    int sB2 = 1 * 128 * LDT + rB0 * LDT + cB0;
    int sB3 = 1 * 128 * LDT + rB1 * LDT + cB0;
    int sB4 = 2 * 128 * LDT + rB0 * LDT + cB0;
    int sB5 = 2 * 128 * LDT + rB1 * LDT + cB0;

    uint4 la0, la1, la2, lb0, lb1, lb2, lb3, lb4, lb5;

    f32x4 acc[2][4] = {};

    CONV_LOAD(0);

    for (int c0 = 0; c0 < Cc; c0 += 64) {
        __syncthreads();              // previous chunk's readers done
        CONV_STORE();
        __syncthreads();              // LDS ready
        if (c0 + 64 < Cc) {
            CONV_LOAD(c0 + 64);       // issue next chunk's loads...
            __builtin_amdgcn_sched_barrier(0);  // ...and PIN them above MFMA
        }
#pragma unroll
        for (int kk = 0; kk < 3; ++kk) {
#pragma unroll
            for (int ks = 0; ks < 2; ++ks) {
                int kof = ks * 32 + quad * 8;
                bf16x8 a0 = *(const bf16x8*)(&As[(wm + l16 + kk) * LDT + kof]);
                bf16x8 a1 = *(const bf16x8*)(&As[(wm + 16 + l16 + kk) * LDT + kof]);
                bf16x8 b0 = *(const bf16x8*)(&Bs[kk * 128 * LDT + (wn + l16) * LDT + kof]);
                bf16x8 b1 = *(const bf16x8*)(&Bs[kk * 128 * LDT + (wn + 16 + l16) * LDT + kof]);
                bf16x8 b2 = *(const bf16x8*)(&Bs[kk * 128 * LDT + (wn + 32 + l16) * LDT + kof]);
                bf16x8 b3 = *(const bf16x8*)(&Bs[kk * 128 * LDT + (wn + 48 + l16) * LDT + kof]);
                acc[0][0] = __builtin_amdgcn_mfma_f32_16x16x32_bf16(a0, b0, acc[0][0], 0, 0, 0);
                acc[0][1] = __builtin_amdgcn_mfma_f32_16x16x32_bf16(a0, b1, acc[0][1], 0, 0, 0);
                acc[0][2] = __builtin_amdgcn_mfma_f32_16x16x32_bf16(a0, b2, acc[0][2], 0, 0, 0);
                acc[0][3] = __builtin_amdgcn_mfma_f32_16x16x32_bf16(a0, b3, acc[0][3], 0, 0, 0);
                acc[1][0] = __builtin_amdgcn_mfma_f32_16x16x32_bf16(a1, b0, acc[1][0], 0, 0, 0);
                acc[1][1] = __builtin_amdgcn_mfma_f32_16x16x32_bf16(a1, b1, acc[1][1], 0, 0, 0);
                acc[1][2] = __builtin_amdgcn_mfma_f32_16x16x32_bf16(a1, b2, acc[1][2], 0, 0, 0);
                acc[1][3] = __builtin_amdgcn_mfma_f32_16x16x32_bf16(a1, b3, acc[1][3], 0, 0, 0);
            }
        }
    }

    // epilogue: C/D layout col=l16, row=quad*4+r ; local row = wm + mt*16 + quad*4 + r
#pragma unroll
    for (int mt = 0; mt < 2; ++mt) {
#pragma unroll
        for (int nt = 0; nt < 4; ++nt) {
            int col = nBase + wn + nt * 16 + l16;
            int trow = t0 + wm + mt * 16 + quad * 4;
            float bv = bias[col];
#pragma unroll
            for (int r = 0; r < 4; ++r) {
                long off = (long)z * sC1 + (long)(trow + r) * ldc + col;
                float v = acc[mt][nt][r] + bv;
                if (resid) v += resid[off];
                if (relu) v = fmaxf(v, 0.f);
                if (outBf) ((__bf16*)Cp)[off] = (__bf16)v;
                else       ((float*)Cp)[off] = v;
            }
        }
    }
}

// =====================================================================
// ======  Fused flash attention (QK^T -> softmax -> PV), DH=192  ======
// =====================================================================
__global__ __launch_bounds__(512) void flash_attn(
    const __bf16* __restrict__ qkv, __bf16* __restrict__ o, int T, float scl)
{
    int z = blockIdx.y;
    int b = z >> 1, h = z & 1;
    const __bf16* base = qkv + (long)b * T * 3 * CD + h * CDH;
    int qBase = blockIdx.x * 128;

    __shared__ __attribute__((aligned(16))) __bf16 Qs[128][200];
    __shared__ __attribute__((aligned(16))) __bf16 Ks[64][200];
    __shared__ __attribute__((aligned(16))) __bf16 Vt[192][72];
    __shared__ __attribute__((aligned(16))) __bf16 Ps[128][72];

    int tid  = threadIdx.x;
    int lane = tid & 63;
    int wave = tid >> 6;
    int quad = lane >> 4;
    int l16  = lane & 15;
    int wq   = wave * 16;

#pragma unroll
    for (int i = 0; i < 6; ++i) {
        int u = tid + i * 512;
        int r = u / 24, c = (u % 24) * 8;
        *(uint4*)(&Qs[r][c]) = *(const uint4*)(base + (long)(qBase + r) * 3 * CD + c);
    }

    f32x4 oacc[12];
#pragma unroll
    for (int j = 0; j < 12; ++j) oacc[j] = (f32x4){0.f, 0.f, 0.f, 0.f};
    float mrow[4], lrow[4];
#pragma unroll
    for (int r = 0; r < 4; ++r) { mrow[r] = -3.0e38f; lrow[r] = 0.f; }

    for (int kv0 = 0; kv0 < T; kv0 += 64) {
        __syncthreads();
#pragma unroll
        for (int i = 0; i < 3; ++i) {
            int u = tid + i * 512;
            int r = u / 24, c = (u % 24) * 8;
            *(uint4*)(&Ks[r][c]) = *(const uint4*)(base + CD + (long)(kv0 + r) * 3 * CD + c);
        }
        // V transpose staging: r = u&63 (kv row), c = (u>>6)*8 (d-block) ->
        // per write-instruction the 64 lanes write 64 consecutive Vt columns
        // (128 contiguous B = all 32 banks, <=2-way).  (R1 fix: was ~24-way.)
#pragma unroll
        for (int i = 0; i < 3; ++i) {
            int u = tid + i * 512;
            int r = u & 63, c = (u >> 6) * 8;
            uint4 pkt = *(const uint4*)(base + 2 * CD + (long)(kv0 + r) * 3 * CD + c);
            const __bf16* v8 = (const __bf16*)&pkt;
#pragma unroll
            for (int j = 0; j < 8; ++j) Vt[c + j][r] = v8[j];
        }
        __syncthreads();

        f32x4 s[4];
#pragma unroll
        for (int nt = 0; nt < 4; ++nt) s[nt] = (f32x4){0.f, 0.f, 0.f, 0.f};
#pragma unroll
        for (int ks = 0; ks < 6; ++ks) {
            bf16x8 aq = *(const bf16x8*)(&Qs[wq + l16][ks * 32 + quad * 8]);
#pragma unroll
            for (int nt = 0; nt < 4; ++nt) {
                bf16x8 bk = *(const bf16x8*)(&Ks[nt * 16 + l16][ks * 32 + quad * 8]);
                s[nt] = __builtin_amdgcn_mfma_f32_16x16x32_bf16(aq, bk, s[nt], 0, 0, 0);
            }
        }
        float alpha[4];
#pragma unroll
        for (int r = 0; r < 4; ++r) {
            float mx = -3.0e38f;
#pragma unroll
            for (int nt = 0; nt < 4; ++nt) {
                s[nt][r] *= scl;
                mx = fmaxf(mx, s[nt][r]);
            }
            mx = fmaxf(mx, __shfl_xor(mx, 1));
            mx = fmaxf(mx, __shfl_xor(mx, 2));
            mx = fmaxf(mx, __shfl_xor(mx, 4));
            mx = fmaxf(mx, __shfl_xor(mx, 8));
            float mnew = fmaxf(mrow[r], mx);
            alpha[r] = __expf(mrow[r] - mnew);
            mrow[r] = mnew;
            float rs = 0.f;
#pragma unroll
            for (int nt = 0; nt < 4; ++nt) {
                float e = __expf(s[nt][r] - mnew);
                s[nt][r] = e;
                rs += e;
            }
            rs += __shfl_xor(rs, 1);
            rs += __shfl_xor(rs, 2);
            rs += __shfl_xor(rs, 4);
            rs += __shfl_xor(rs, 8);
            lrow[r] = lrow[r] * alpha[r] + rs;
        }
#pragma unroll
        for (int r = 0; r < 4; ++r)
#pragma unroll
            for (int nt = 0; nt < 4; ++nt)
                Ps[wq + quad * 4 + r][nt * 16 + l16] = (__bf16)s[nt][r];
#pragma unroll
        for (int j = 0; j < 12; ++j)
#pragma unroll
            for (int r = 0; r < 4; ++r) oacc[j][r] *= alpha[r];
#pragma unroll
        for (int ks2 = 0; ks2 < 2; ++ks2) {
            bf16x8 ap = *(const bf16x8*)(&Ps[wq + l16][ks2 * 32 + quad * 8]);
#pragma unroll
            for (int nt = 0; nt < 12; ++nt) {
                bf16x8 bv = *(const bf16x8*)(&Vt[nt * 16 + l16][ks2 * 32 + quad * 8]);
                oacc[nt] = __builtin_amdgcn_mfma_f32_16x16x32_bf16(ap, bv, oacc[nt], 0, 0, 0);
            }
        }
    }

    __bf16* ob = o + ((long)b * T + qBase + wq + quad * 4) * CD + h * CDH + l16;
#pragma unroll
    for (int r = 0; r < 4; ++r) {
        float inv = 1.0f / lrow[r];
#pragma unroll
        for (int nt = 0; nt < 12; ++nt)
            ob[(long)r * CD + nt * 16] = (__bf16)(oacc[nt][r] * inv);
    }
}

// ---- LN: out32 = LN(a)*g+be ; bf16 padded copy ----
__global__ __launch_bounds__(CD) void ln_res(const float* __restrict__ a,
    const float* __restrict__ g, const float* __restrict__ be,
    float* __restrict__ out32, __bf16* __restrict__ outbf, int Tlog2)
{
    long r = blockIdx.x;
    int d = threadIdx.x;
    float v = a[r * CD + d];
    float s1 = v, s2 = v * v;
#pragma unroll
    for (int off = 32; off > 0; off >>= 1) {
        s1 += __shfl_down(s1, off);
        s2 += __shfl_down(s2, off);
    }
    __shared__ float sh1[CD / 64], sh2[CD / 64];
    int wv = d >> 6, ln = d & 63;
    if (ln == 0) { sh1[wv] = s1; sh2[wv] = s2; }
    __syncthreads();
    if (d == 0) {
        float t1 = 0.f, t2 = 0.f;
        for (int i = 0; i < CD / 64; ++i) { t1 += sh1[i]; t2 += sh2[i]; }
        sh1[0] = t1; sh2[0] = t2;
    }
    __syncthreads();
    float mean = sh1[0] * (1.0f / CD);
    float var  = sh2[0] * (1.0f / CD) - mean * mean;
    float res = (v - mean) * rsqrtf(var + 1e-5f) * g[d] + be[d];
    out32[r * CD + d] = res;
    int T = 1 << Tlog2;
    long bb = r >> Tlog2; int t = (int)(r & (T - 1));
    outbf[(bb * (T + 2) + t + 1) * CD + d] = (__bf16)res;
}

__global__ __launch_bounds__(CD) void f32_to_padbf16(const float* __restrict__ in,
    __bf16* __restrict__ out, int Tlog2)
{
    long r = blockIdx.x;
    int d = threadIdx.x;
    int T = 1 << Tlog2;
    long b = r >> Tlog2; int t = (int)(r & (T - 1));
    out[(b * (T + 2) + t + 1) * CD + d] = (__bf16)in[r * CD + d];
}

__global__ void zero_pads(__bf16* __restrict__ p, int Tp2, int C)
{
    int b = blockIdx.x >> 1;
    int which = blockIdx.x & 1;
    long row = (long)b * Tp2 + (which ? Tp2 - 1 : 0);
    for (int c = threadIdx.x; c < C; c += blockDim.x) p[row * C + c] = (__bf16)0.f;
}

__global__ __launch_bounds__(256) void tr_f32_bf16(const float* __restrict__ in,
    __bf16* __restrict__ out, int R, int C)
{
    __shared__ float t[32][33];
    int c0 = blockIdx.x * 32, r0 = blockIdx.y * 32;
    int tx = threadIdx.x & 31, ty = threadIdx.x >> 5;
#pragma unroll
    for (int i = 0; i < 4; ++i) {
        int rr = ty * 4 + i;
        int r = r0 + rr, c = c0 + tx;
        if (r < R && c < C) t[rr][tx] = in[(long)r * C + c];
    }
    __syncthreads();
#pragma unroll
    for (int i = 0; i < 4; ++i) {
        int cc = ty * 4 + i;
        int c = c0 + cc, r = r0 + tx;
        if (c < C && r < R) out[(long)c * R + r] = (__bf16)t[tx][cc];
    }
}

__global__ void convw_bf16(const float* __restrict__ w, __bf16* __restrict__ wt,
                           int O, int Cc)
{
    long total = (long)O * 3 * Cc;
    int KC = 3 * Cc;
    for (long i = (long)blockIdx.x * blockDim.x + threadIdx.x; i < total;
         i += (long)gridDim.x * blockDim.x) {
        int j = (int)(i % KC); long o = i / KC;
        int kk = j / Cc, c = j % Cc;
        wt[i] = (__bf16)w[(o * Cc + c) * 3 + kk];
    }
}

__global__ __launch_bounds__(CD) void embed_pe_kernel(const int* __restrict__ x,
    const float* __restrict__ emb, float* __restrict__ h)
{
    int bs = blockIdx.x;
    int d  = threadIdx.x;
    int s  = bs & (CS - 1);
    int tok = x[bs];
    int i = d >> 1;
    float ang = (float)s * powf(10000.0f, -2.0f * (float)i / (float)CD);
    float pe = (d & 1) ? cosf(ang) : sinf(ang);
    h[(size_t)bs * CD + d] = emb[(size_t)tok * CD + d] + pe;
}

__global__ __launch_bounds__(CS) void lenreg_kernel(const int* __restrict__ y,
    int* __restrict__ idx, int* __restrict__ totals)
{
    __shared__ int ends[CS];
    int b = blockIdx.x, tid = threadIdx.x;
    if (tid == 0) {
        int acc = 0;
        for (int s = 0; s < CS; ++s) { acc += y[b * CS + s]; ends[s] = acc; }
    }
    __syncthreads();
    for (int t = tid; t < CLOUT; t += CS) idx[b * CLOUT + t] = CS - 1;
    if (tid == 0) totals[b] = ends[CS - 1];
    __syncthreads();
    int st = (tid == 0) ? 0 : ends[tid - 1];
    int en = ends[tid];
    for (int t = st; t < en; ++t) idx[b * CLOUT + t] = tid;
}

__global__ __launch_bounds__(CD) void gather_dual(const float* __restrict__ hph,
    const int* __restrict__ idx, const int* __restrict__ tot,
    float* __restrict__ h32, __bf16* __restrict__ hbf, int chunkBase)
{
    int rl = blockIdx.x;
    int rg = chunkBase + rl;
    int b = rg >> 10, t = rg & (CLOUT - 1);
    int d = threadIdx.x;
    int src = idx[rg];
    float v = (t < tot[b]) ? hph[((long)b * CS + src) * CD + d] : 0.f;
    h32[(long)rl * CD + d] = v;
    long bl = rl >> 10; int tl = rl & (CLOUT - 1);
    hbf[(bl * (CLOUT + 2) + tl + 1) * CD + d] = (__bf16)v;
}

// =====================================================================
// ===============  bf16 path driver  ==================================
// =====================================================================

static inline void mm(hipStream_t st, const __bf16* A, long lda, long sA1, long sA2,
    const __bf16* Bt, long ldb, long sB1, long sB2, const float* bias,
    const float* resid, void* C, long ldc, long sC1, long sC2, int M, int N, int K,
    int nz, int zdiv, int relu, int outBf, float scale)
{
    dim3 g((N + 127) / 128, M / 128, nz), b(256, 1, 1);
    hipLaunchKernelGGL(mm_bf16, g, b, 0, st, A, lda, sA1, sA2, Bt, ldb, sB1, sB2,
                       bias, resid, C, ldc, sC1, sC2, M, N, K, zdiv, relu, outBf, scale);
}

struct Scr {
    float *h32, *x32, *tmp32;
    __bf16 *hbf, *xbf, *qkv, *c1p, *o;
};

static size_t scr_layout(char* base, int NB, int T, Scr* s)
{
    auto align = [](size_t v) { return (v + 255) & ~(size_t)255; };
    size_t off = 0;
    long Tp2 = T + 2;
    if (s) s->h32 = (float*)(base + off);
    off = align(off + (size_t)NB * T * CD * 4);
    if (s) s->x32 = (float*)(base + off);
    off = align(off + (size_t)NB * T * CD * 4);
    if (s) s->tmp32 = (float*)(base + off);
    off = align(off + (size_t)NB * T * CD * 4);
    if (s) s->hbf = (__bf16*)(base + off);
    off = align(off + (size_t)NB * Tp2 * CD * 2);
    if (s) s->xbf = (__bf16*)(base + off);
    off = align(off + (size_t)NB * Tp2 * CD * 2);
    if (s) s->qkv = (__bf16*)(base + off);
    off = align(off + (size_t)NB * T * 3 * CD * 2);
    if (s) s->c1p = (__bf16*)(base + off);
    off = align(off + (size_t)NB * Tp2 * CDF * 2);
    if (s) s->o = (__bf16*)(base + off);
    off = align(off + (size_t)NB * T * CD * 2);
    return off;
}

// per-layer bf16 weight offsets (elements)
constexpr long W_QKV = 0;
constexpr long W_OUT = 442368;
constexpr long W_C1  = 589824;
constexpr long W_C2  = 2359296;
constexpr long WLAYER = 4128768;
constexpr long WSTACK = 6 * WLAYER;
constexpr long WTOT   = WSTACK + 30720;

static void convert_stack_weights(hipStream_t st, __bf16* wbuf,
    const float* qkv_w, const float* out_w, const float* c1w, const float* c2w)
{
    for (int l = 0; l < CL; ++l) {
        __bf16* wl = wbuf + (long)l * WLAYER;
        hipLaunchKernelGGL(tr_f32_bf16, dim3(36, 12), dim3(256), 0, st,
                           qkv_w + (long)l * CD * 3 * CD, wl + W_QKV, CD, 3 * CD);
        hipLaunchKernelGGL(tr_f32_bf16, dim3(12, 12), dim3(256), 0, st,
                           out_w + (long)l * CD * CD, wl + W_OUT, CD, CD);
        hipLaunchKernelGGL(convw_bf16, dim3(2048), dim3(256), 0, st,
                           c1w + (long)l * CDF * CD * 3, wl + W_C1, CDF, CD);
        hipLaunchKernelGGL(convw_bf16, dim3(2048), dim3(256), 0, st,
                           c2w + (long)l * CD * CDF * 3, wl + W_C2, CD, CDF);
    }
}

static void fft_block_bf16(hipStream_t st, const Scr& S, int NBc, int T, int tlog2,
    float* h32, const __bf16* wl,
    const float* qkv_b, const float* out_b,
    const float* g1, const float* b1, const float* c1b, const float* c2b,
    const float* g2, const float* b2)
{
    const int M = NBc * T;
    const long Tp2 = T + 2;
    const float scl = 1.0f / sqrtf((float)CDH);

    // qkv = h @ Wqkv + b
    mm(st, S.hbf + CD, CD, Tp2 * CD, 0, wl + W_QKV, CD, 0, 0, qkv_b, nullptr,
       S.qkv, 3 * CD, (long)T * 3 * CD, 0, T, 3 * CD, CD, NBc, 1, 0, 1, 1.f);

    // fused attention
    hipLaunchKernelGGL(flash_attn, dim3(T / 128, NBc * CH), dim3(512), 0, st,
                       S.qkv, S.o, T, scl);

    // tmp = o @ Wout + b + h (residual fused)
    mm(st, S.o, CD, 0, 0, wl + W_OUT, CD, 0, 0, out_b, h32,
       S.tmp32, CD, 0, 0, M, CD, CD, 1, 1, 0, 0, 1.f);

    // x = LN(tmp)
    hipLaunchKernelGGL(ln_res, dim3(M), dim3(CD), 0, st,
                       S.tmp32, g1, b1, S.x32, S.xbf, tlog2);

    // conv1: relu(conv(x)) -> c1p rows 1..T (bf16); reg-prefetch conv
    hipLaunchKernelGGL(conv_mfma4, dim3(CDF / 128, T / 128, NBc), dim3(512), 0, st,
                       S.xbf, wl + W_C1, c1b, nullptr,
                       (void*)(S.c1p + CDF), (long)CDF, Tp2 * CDF,
                       T, (int)Tp2, CD, CDF, 1, 1);

    // conv2 + resid -> tmp32 (fp32)
    hipLaunchKernelGGL(conv_mfma4, dim3(CD / 128, T / 128, NBc), dim3(512), 0, st,
                       S.c1p, wl + W_C2, c2b, S.x32,
                       S.tmp32, (long)CD, (long)T * CD,
                       T, (int)Tp2, CDF, CD, 0, 0);

    // h = LN(tmp)
    hipLaunchKernelGGL(ln_res, dim3(M), dim3(CD), 0, st,
                       S.tmp32, g2, b2, h32, S.hbf, tlog2);
}

extern "C" void kernel_launch(void* const* d_in, const int* in_sizes, int n_in,
                              void* d_out, int out_size, void* d_ws, size_t ws_size,
                              hipStream_t stream)
{
    (void)in_sizes; (void)out_size;

    const int* x = (const int*)d_in[0];
    const int* y = (const int*)d_in[1];
    const float* P[40];
    for (int i = 0; i < n_in && i < 40; ++i) P[i] = (const float*)d_in[i];

    size_t wbufB  = ((size_t)WTOT * 2 + 255) & ~(size_t)255;
    size_t hphB   = ((size_t)CB * CS * CD * 4 + 255) & ~(size_t)255;
    size_t idxB   = (((size_t)CB * CLOUT + CB) * 4 + 255) & ~(size_t)255;
    size_t fixedB = wbufB + hphB + idxB;

    size_t scrB = (ws_size > fixedB) ? (ws_size - fixedB) : 0;

    int NBmel = 1;
    for (int cand = 16; cand >= 1; cand >>= 1)
        if (scr_layout(nullptr, cand, CLOUT, nullptr) <= scrB) { NBmel = cand; break; }

    int NBph = 1;
    for (int cand = 16; cand >= 1; cand >>= 1)
        if (scr_layout(nullptr, cand, CS, nullptr) <= scrB) { NBph = cand; break; }

    char* base = (char*)d_ws;
    __bf16* wbuf = (__bf16*)base;
    float*  hPh  = (float*)(base + wbufB);
    int*    idxb = (int*)(base + wbufB + hphB);
    int*    totb = idxb + (long)CB * CLOUT;
    char*   scrbase = base + fixedB;

    // ================= phoneme encoder =================
    convert_stack_weights(stream, wbuf, P[3], P[5], P[9], P[11]);

    Scr Sp; scr_layout(scrbase, NBph, CS, &Sp);
    hipLaunchKernelGGL(zero_pads, dim3(NBph * 2), dim3(256), 0, stream, Sp.hbf, CS + 2, CD);
    hipLaunchKernelGGL(zero_pads, dim3(NBph * 2), dim3(256), 0, stream, Sp.xbf, CS + 2, CD);
    hipLaunchKernelGGL(zero_pads, dim3(NBph * 2), dim3(256), 0, stream, Sp.c1p, CS + 2, CDF);

    hipLaunchKernelGGL(embed_pe_kernel, dim3(CB * CS), dim3(CD), 0, stream, x, P[2], hPh);

    for (int c = 0; c < CB / NBph; ++c) {
        float* hch = hPh + (long)c * NBph * CS * CD;
        hipLaunchKernelGGL(f32_to_padbf16, dim3(NBph * CS), dim3(CD), 0, stream,
                           hch, Sp.hbf, 7);
        for (int l = 0; l < CL; ++l)
            fft_block_bf16(stream, Sp, NBph, CS, 7, hch, wbuf + (long)l * WLAYER,
                           P[4] + (long)l * 3 * CD, P[6] + (long)l * CD,
                           P[7] + (long)l * CD, P[8] + (long)l * CD,
                           P[10] + (long)l * CDF, P[12] + (long)l * CD,
                           P[13] + (long)l * CD, P[14] + (long)l * CD);
    }

    // ================= length regulation =================
    hipLaunchKernelGGL(lenreg_kernel, dim3(CB), dim3(CS), 0, stream, y, idxb, totb);

    // ================= mel decoder =================
    convert_stack_weights(stream, wbuf, P[15], P[17], P[21], P[23]);
    hipLaunchKernelGGL(tr_f32_bf16, dim3(3, 12), dim3(256), 0, stream,
                       P[37], wbuf + WSTACK, CD, CNM);

    Scr Sm; scr_layout(scrbase, NBmel, CLOUT, &Sm);
    hipLaunchKernelGGL(zero_pads, dim3(NBmel * 2), dim3(256), 0, stream, Sm.hbf, CLOUT + 2, CD);
    hipLaunchKernelGGL(zero_pads, dim3(NBmel * 2), dim3(256), 0, stream, Sm.xbf, CLOUT + 2, CD);
    hipLaunchKernelGGL(zero_pads, dim3(NBmel * 2), dim3(256), 0, stream, Sm.c1p, CLOUT + 2, CDF);

    for (int c = 0; c < CB / NBmel; ++c) {
        hipLaunchKernelGGL(gather_dual, dim3(NBmel * CLOUT), dim3(CD), 0, stream,
                           hPh, idxb, totb, Sm.h32, Sm.hbf, c * NBmel * CLOUT);
        for (int l = 0; l < CL; ++l)
            fft_block_bf16(stream, Sm, NBmel, CLOUT, 10, Sm.h32, wbuf + (long)l * WLAYER,
                           P[16] + (long)l * 3 * CD, P[18] + (long)l * CD,
                           P[19] + (long)l * CD, P[20] + (long)l * CD,
                           P[22] + (long)l * CDF, P[24] + (long)l * CD,
                           P[25] + (long)l * CD, P[26] + (long)l * CD);
        // final projection for this chunk
        mm(stream, Sm.hbf + CD, CD, (long)(CLOUT + 2) * CD, 0,
           wbuf + WSTACK, CD, 0, 0, P[38], nullptr,
           (float*)d_out + (long)c * NBmel * CLOUT * CNM, CNM, (long)CLOUT * CNM, 0,
           CLOUT, CNM, CD, NBmel, 1, 0, 0, 1.f);
    }
}